// Round 4
// baseline (16144.966 us; speedup 1.0000x reference)
//
#include <hip/hip_runtime.h>
#include <hip/hip_bf16.h>
#include <cstdio>

typedef __hip_bfloat16 bf16;

#define N_TOK 65536
#define C_DIM 192
#define PLANE 12582912   // N_TOK * 192 elements (one q/k/v plane)

__device__ __forceinline__ float b2f(bf16 v) { return __bfloat162float(v); }
__device__ __forceinline__ bf16 f2b(float v) { return __float2bfloat16(v); }
// adaptive load of an INPUT tensor element (dtype decided at runtime)
__device__ __forceinline__ float ldA(const void* p, size_t i, int f32) {
  return f32 ? ((const float*)p)[i] : b2f(((const bf16*)p)[i]);
}

// ---------------- dtype detector: bf16-lens exponent statistics ----------------
__global__ void detect_kernel(const unsigned short* __restrict__ xh, int* __restrict__ flag) {
  if (threadIdx.x == 0) {
    int crazy = 0;
    for (int i = 0; i < 256; ++i) {
      int e = (xh[i] >> 7) & 0xFF;   // bf16 exponent field
      if (e >= 0xF0 || (e >= 1 && e <= 0x60)) ++crazy;
    }
    int f32 = (crazy >= 16) ? 1 : 0;   // packed f32 -> ~44% crazy; true bf16 -> ~0
    *flag = f32;
    const unsigned int* xw = (const unsigned int*)xh;
    printf("[detect] raw=%08x %08x %08x %08x crazy=%d -> f32=%d\n",
           xw[0], xw[1], xw[2], xw[3], crazy, f32);
  }
}

// ---------------- NaN/Inf scan (diagnostic) ----------------
// code: 0 = bf16, 1 = f32, 2 = adaptive (input dtype)
__global__ void scan_kernel(const void* __restrict__ p, int n, int code, int stage,
                            const int* __restrict__ flag) {
  __shared__ int s_nan, s_inf;
  if (threadIdx.x == 0) { s_nan = 0; s_inf = 0; }
  __syncthreads();
  int f32 = (code == 1) || (code == 2 && *flag);
  int ln = 0, li = 0;
  for (int i = threadIdx.x; i < n; i += 256) {
    float v = f32 ? ((const float*)p)[i] : b2f(((const bf16*)p)[i]);
    if (isnan(v)) ++ln; else if (isinf(v)) ++li;
  }
  atomicAdd(&s_nan, ln); atomicAdd(&s_inf, li);
  __syncthreads();
  if (threadIdx.x == 0) {
    float v0 = f32 ? ((const float*)p)[0] : b2f(((const bf16*)p)[0]);
    float v1 = f32 ? ((const float*)p)[1] : b2f(((const bf16*)p)[1]);
    printf("[scan %d] f32=%d nan=%d inf=%d v0=%g v1=%g\n", stage, f32, s_nan, s_inf, v0, v1);
  }
}

// ---------------- LayerNorm: adaptive/bf16 in -> bf16 out; optional window gather ------
__global__ __launch_bounds__(256) void ln_kernel(const void* __restrict__ x,
    const void* __restrict__ g, const void* __restrict__ b, bf16* __restrict__ out,
    int windowize, int xIsBf16Fixed, const int* __restrict__ flag) {
  int wf32 = *flag;
  int f32 = xIsBf16Fixed ? 0 : wf32;
  int token = blockIdx.x * 4 + (threadIdx.x >> 6);
  int lane = threadIdx.x & 63;
  size_t base = (size_t)token * C_DIM;
  float v0 = ldA(x, base + lane, f32);
  float v1 = ldA(x, base + lane + 64, f32);
  float v2 = ldA(x, base + lane + 128, f32);
  float s = v0 + v1 + v2;
  float s2 = v0 * v0 + v1 * v1 + v2 * v2;
  #pragma unroll
  for (int o = 32; o > 0; o >>= 1) { s += __shfl_xor(s, o, 64); s2 += __shfl_xor(s2, o, 64); }
  float mu = s * (1.f / 192.f);
  float var = s2 * (1.f / 192.f) - mu * mu;
  float rstd = rsqrtf(var + 1e-5f);
  int row = token;
  if (windowize) {
    int d = token >> 12, h = (token >> 6) & 63, w = token & 63;
    int win = ((d >> 2) << 6) + ((h >> 3) << 3) + (w >> 3);
    int t = ((d & 3) << 6) + ((h & 7) << 3) + (w & 7);
    row = win * 256 + t;
  }
  bf16* po = out + (size_t)row * C_DIM;
  po[lane]       = f2b((v0 - mu) * rstd * ldA(g, lane, wf32)       + ldA(b, lane, wf32));
  po[lane + 64]  = f2b((v1 - mu) * rstd * ldA(g, lane + 64, wf32)  + ldA(b, lane + 64, wf32));
  po[lane + 128] = f2b((v2 - mu) * rstd * ldA(g, lane + 128, wf32) + ldA(b, lane + 128, wf32));
}

// ---------------- Generic tiled GEMM, f32 accumulate ----------------
// A: M x K intermediate (bf16, or f32 if aF32). B/bias: INPUT weights (adaptive), with
// element offsets boff (B) / biasoff. res: x (adaptive, mode 3) or bf16 X1 (mode 1).
// mode 0: out bf16 = v (+bias)
// mode 1: out (adaptive dtype) = b2f(res) + v + bias     (final output)
// mode 2: qkv scatter into bf16 q/k/v planes (+bias)
// mode 3: out bf16 natural = res(adaptive) + v + bias, window->natural remap (proj)
// mode 4: out f32 += v
__global__ __launch_bounds__(256) void gemm_kernel(const void* __restrict__ Av,
    const void* __restrict__ B, const void* __restrict__ bias,
    const void* __restrict__ res, void* __restrict__ out,
    int Nc, int K, int ldb, int mode, int aF32,
    size_t boff, size_t biasoff, const int* __restrict__ flag) {
  int f32 = *flag;
  __shared__ float As[16][68];
  __shared__ float Bs[16][64];
  int tid = threadIdx.x;
  int tr = tid >> 4, tc = tid & 15;
  int rowBase = blockIdx.y * 64;
  int colBase = blockIdx.x * 64;
  float acc[4][4] = {};
  for (int k0 = 0; k0 < K; k0 += 16) {
    #pragma unroll
    for (int i = 0; i < 4; ++i) {
      int idx = tid + i * 256;
      int m = idx >> 4, kk = idx & 15;
      size_t ai = (size_t)(rowBase + m) * K + (k0 + kk);
      As[kk][m] = aF32 ? ((const float*)Av)[ai] : b2f(((const bf16*)Av)[ai]);
      int kb = idx >> 6, nb = idx & 63;
      int col = colBase + nb;
      Bs[kb][nb] = (col < Nc) ? ldA(B, boff + (size_t)(k0 + kb) * ldb + col, f32) : 0.f;
    }
    __syncthreads();
    #pragma unroll
    for (int kk = 0; kk < 16; ++kk) {
      float a[4], bb[4];
      #pragma unroll
      for (int i = 0; i < 4; ++i) a[i] = As[kk][tr * 4 + i];
      #pragma unroll
      for (int j = 0; j < 4; ++j) bb[j] = Bs[kk][tc * 4 + j];
      #pragma unroll
      for (int i = 0; i < 4; ++i)
        #pragma unroll
        for (int j = 0; j < 4; ++j) acc[i][j] += a[i] * bb[j];
    }
    __syncthreads();
  }
  #pragma unroll
  for (int i = 0; i < 4; ++i) {
    int r = rowBase + tr * 4 + i;
    #pragma unroll
    for (int j = 0; j < 4; ++j) {
      int c = colBase + tc * 4 + j;
      if (c >= Nc) continue;
      float v = acc[i][j];
      if (bias) v += ldA(bias, biasoff + c, f32);
      if (mode == 0) {
        ((bf16*)out)[(size_t)r * Nc + c] = f2b(v);
      } else if (mode == 1) {
        float o = b2f(((const bf16*)res)[(size_t)r * Nc + c]) + v;
        if (f32) ((float*)out)[(size_t)r * Nc + c] = o;
        else     ((bf16*)out)[(size_t)r * Nc + c] = f2b(o);
      } else if (mode == 2) {
        int which = c / 192, rem = c - which * 192;
        int hd = rem >> 5, e = rem & 31;
        int win = r >> 8, t = r & 255;
        ((bf16*)out)[(size_t)which * PLANE +
                     ((size_t)((win * 6 + hd) * 256 + t)) * 32 + e] = f2b(v);
      } else if (mode == 3) {
        int win = r >> 8, t = r & 255;
        int d = ((win >> 6) << 2) + (t >> 6);
        int h = (((win >> 3) & 7) << 3) + ((t >> 3) & 7);
        int w = ((win & 7) << 3) + (t & 7);
        int n = (d << 12) + (h << 6) + w;
        ((bf16*)out)[(size_t)n * C_DIM + c] = f2b(ldA(res, (size_t)n * C_DIM + c, f32) + v);
      } else {  // mode 4: f32 accumulate
        ((float*)out)[(size_t)r * Nc + c] += v;
      }
    }
  }
}

// ---------------- Attention: one block per (win, head), thread per query row -----------
__global__ __launch_bounds__(256) void attn_kernel(const bf16* __restrict__ qkv,
    const void* __restrict__ rel_bias, bf16* __restrict__ out,
    const int* __restrict__ flag) {
  int f32 = *flag;
  __shared__ float sk[256 * 32];
  __shared__ bf16  sv[256 * 32];
  __shared__ float sb[1575];
  __shared__ int   sg[256];
  int head = blockIdx.x;
  int win  = blockIdx.y;
  int wh = win * 6 + head;
  const bf16* qp = qkv + (size_t)wh * 8192;
  const bf16* kp = qkv + PLANE + (size_t)wh * 8192;
  const bf16* vp = qkv + 2 * (size_t)PLANE + (size_t)wh * 8192;
  int tid = threadIdx.x;
  for (int idx = tid; idx < 8192; idx += 256) {
    sk[idx] = b2f(kp[idx]);
    sv[idx] = vp[idx];
  }
  for (int idx = tid; idx < 1575; idx += 256) sb[idx] = ldA(rel_bias, (size_t)idx * 6 + head, f32);
  {
    int t = tid;
    int d = ((win >> 6) << 2) + (t >> 6);
    int h = (((win >> 3) & 7) << 3) + ((t >> 3) & 7);
    int w = ((win & 7) << 3) + (t & 7);
    int d2 = (d + 2) & 15, h2 = (h + 4) & 63, w2 = (w + 4) & 63;
    sg[t] = ((d2 >> 2) << 6) + ((h2 >> 3) << 3) + (w2 >> 3);
  }
  __syncthreads();
  int t = tid;
  float q[32];
  const bf16* qr = qp + t * 32;
  #pragma unroll
  for (int e = 0; e < 32; ++e) q[e] = b2f(qr[e]) * 0.17677669529663687f;
  int td = t >> 6, th = (t >> 3) & 7, tw = t & 7;
  int gt = sg[t];
  float m = 3.0f, l = 0.f;
  float acc[32];
  #pragma unroll
  for (int e = 0; e < 32; ++e) acc[e] = 0.f;
  for (int j = 0; j < 256; ++j) {
    int rel = ((td - (j >> 6) + 3) * 15 + (th - ((j >> 3) & 7) + 7)) * 15 + (tw - (j & 7) + 7);
    float s = sb[rel];
    if (sg[j] != gt) s -= 100.f;
    const float* kr = sk + j * 32;
    float d0 = 0.f, d1 = 0.f, d2 = 0.f, d3 = 0.f;
    #pragma unroll
    for (int e = 0; e < 32; e += 4) {
      d0 += q[e] * kr[e];         d1 += q[e + 1] * kr[e + 1];
      d2 += q[e + 2] * kr[e + 2]; d3 += q[e + 3] * kr[e + 3];
    }
    s += (d0 + d1) + (d2 + d3);
    float p;
    if (s > m) {
      float corr = __expf(m - s);
      l *= corr;
      #pragma unroll
      for (int e = 0; e < 32; ++e) acc[e] *= corr;
      m = s; p = 1.f;
    } else {
      p = __expf(s - m);
    }
    l += p;
    const bf16* vr = sv + j * 32;
    #pragma unroll
    for (int e = 0; e < 32; ++e) acc[e] += p * b2f(vr[e]);
  }
  float inv = 1.f / l;
  bf16* po = out + (size_t)(win * 256 + t) * C_DIM + head * 32;
  #pragma unroll
  for (int e = 0; e < 32; ++e) po[e] = f2b(acc[e] * inv);
}

// ---------------- Depthwise 3x3x3 conv + bias + GELU on a 96-channel chunk -------------
__global__ __launch_bounds__(256) void dwconv_kernel(const bf16* __restrict__ in,
    const void* __restrict__ wgt, const void* __restrict__ wb, bf16* __restrict__ out,
    int cbase, const int* __restrict__ flag) {
  int f32 = *flag;
  int idx = blockIdx.x * 256 + threadIdx.x;   // < 65536*96
  int n = idx / 96, c = idx - n * 96;
  int cg = cbase + c;
  int d = n >> 12, h = (n >> 6) & 63, w = n & 63;
  float s = ldA(wb, cg, f32);
  #pragma unroll
  for (int kd = 0; kd < 3; ++kd) {
    int dd = d + kd - 1;
    if ((unsigned)dd >= 16u) continue;
    #pragma unroll
    for (int kh = 0; kh < 3; ++kh) {
      int hh = h + kh - 1;
      if ((unsigned)hh >= 64u) continue;
      #pragma unroll
      for (int kw = 0; kw < 3; ++kw) {
        int ww = w + kw - 1;
        if ((unsigned)ww >= 64u) continue;
        int nbr = (dd << 12) + (hh << 6) + ww;
        s += b2f(in[(size_t)nbr * 96 + c]) * ldA(wgt, (size_t)cg * 27 + kd * 9 + kh * 3 + kw, f32);
      }
    }
  }
  float gel = 0.5f * s * (1.f + erff(s * 0.70710678118654752f));
  out[(size_t)n * 96 + c] = f2b(gel);
}

// ---------------- zero f32 buffer (float4 granularity) ----------------
__global__ __launch_bounds__(256) void zero_kernel(float4* __restrict__ p) {
  p[(size_t)blockIdx.x * 256 + threadIdx.x] = float4{0.f, 0.f, 0.f, 0.f};
}

extern "C" void kernel_launch(void* const* d_in, const int* in_sizes, int n_in,
                              void* d_out, int out_size, void* d_ws, size_t ws_size,
                              hipStream_t stream) {
  const void* x      = d_in[0];
  const void* n1g    = d_in[1];
  const void* n1b    = d_in[2];
  const void* qkv_w  = d_in[3];
  const void* qkv_b  = d_in[4];
  const void* relb   = d_in[5];
  const void* proj_w = d_in[6];
  const void* proj_b = d_in[7];
  const void* n2g    = d_in[8];
  const void* n2b    = d_in[9];
  const void* fc1_A  = d_in[10];
  const void* fc1_Bw = d_in[11];
  const void* fc1_Bb = d_in[12];
  const void* dw_w   = d_in[13];
  const void* dw_b   = d_in[14];
  const void* fc2_A  = d_in[15];
  const void* fc2_Bw = d_in[16];
  const void* fc2_Bb = d_in[17];

  fprintf(stderr, "[kernel_launch] ws_size=%zu out_size=%d n_in=%d\n",
          ws_size, out_size, n_in);

  // ws peak = 120 MiB (+flag at 200 MiB):
  //   [  0, 72): QKV  -> then X1 [0,24) + T1 [24,72)
  //   [ 72, 84): F1 chunk (N x 96 bf16)
  //   [ 84, 96): F2 chunk (N x 96 bf16)
  //   [ 96,120): T2 accumulator (N x 96 f32)
  char* ws = (char*)d_ws;
  bf16* SCR = (bf16*)d_out;                        // H1 / ATT / H2 scratch (24 MiB)
  bf16* QKV = (bf16*)(ws);
  bf16* X1  = (bf16*)(ws);
  bf16* T1  = (bf16*)(ws + (size_t)24 * 1048576);
  bf16* F1c = (bf16*)(ws + (size_t)72 * 1048576);
  bf16* F2c = (bf16*)(ws + (size_t)84 * 1048576);
  float* T2 = (float*)(ws + (size_t)96 * 1048576);
  int* FLAG = (int*)(ws + (size_t)200 * 1048576);

  // 0. dtype detect + input scan
  detect_kernel<<<1, 64, 0, stream>>>((const unsigned short*)x, FLAG);
  scan_kernel<<<1, 256, 0, stream>>>(x, 1048576, 2, 0, FLAG);
  // 1. LN1 + window gather -> SCR (H1)
  ln_kernel<<<N_TOK / 4, 256, 0, stream>>>(x, n1g, n1b, SCR, 1, 0, FLAG);
  scan_kernel<<<1, 256, 0, stream>>>(SCR, 1048576, 0, 1, FLAG);
  // 2. QKV gemm (window rows), scatter to q/k/v planes
  gemm_kernel<<<dim3(9, 1024), 256, 0, stream>>>(SCR, qkv_w, qkv_b, nullptr, QKV,
                                                 576, 192, 576, 2, 0, 0, 0, FLAG);
  scan_kernel<<<1, 256, 0, stream>>>(QKV, 1048576, 0, 2, FLAG);
  // 3. windowed attention -> SCR (ATT)
  attn_kernel<<<dim3(6, 256), 256, 0, stream>>>(QKV, relb, SCR, FLAG);
  scan_kernel<<<1, 256, 0, stream>>>(SCR, 1048576, 0, 3, FLAG);
  // 4. proj + residual(x), window -> natural -> X1
  gemm_kernel<<<dim3(3, 1024), 256, 0, stream>>>(SCR, proj_w, proj_b, x, X1,
                                                 192, 192, 192, 3, 0, 0, 0, FLAG);
  scan_kernel<<<1, 256, 0, stream>>>(X1, 1048576, 0, 4, FLAG);
  // 5. LN2 -> SCR (H2)
  ln_kernel<<<N_TOK / 4, 256, 0, stream>>>(X1, n2g, n2b, SCR, 0, 1, FLAG);
  // 6. fc1_A: (N,192)@(192,384) -> T1
  gemm_kernel<<<dim3(6, 1024), 256, 0, stream>>>(SCR, fc1_A, nullptr, nullptr, T1,
                                                 384, 192, 384, 0, 0, 0, 0, FLAG);
  scan_kernel<<<1, 256, 0, stream>>>(T1, 1048576, 0, 6, FLAG);
  // 7. zero T2
  zero_kernel<<<6144, 256, 0, stream>>>((float4*)T2);
  // 8. MixFFN middle, chunked over HIDDEN in 8 x 96 channels
  for (int k = 0; k < 8; ++k) {
    // 8a. fc1_B chunk: (N,384)@(384,96 cols at 96k)+b -> F1c
    gemm_kernel<<<dim3(2, 1024), 256, 0, stream>>>(T1, fc1_Bw, fc1_Bb, nullptr, F1c,
                                                   96, 384, 768, 0, 0,
                                                   (size_t)96 * k, (size_t)96 * k, FLAG);
    // 8b. depthwise conv + GELU chunk -> F2c
    dwconv_kernel<<<24576, 256, 0, stream>>>(F1c, dw_w, dw_b, F2c, 96 * k, FLAG);
    // 8c. fc2_A chunk: T2 += (N,96)@(rows 96k..96k+96 of fc2_A)
    gemm_kernel<<<dim3(2, 1024), 256, 0, stream>>>(F2c, fc2_A, nullptr, nullptr, T2,
                                                   96, 96, 96, 4, 0,
                                                   (size_t)96 * k * 96, 0, FLAG);
  }
  scan_kernel<<<1, 256, 0, stream>>>(T2, 1048576, 1, 9, FLAG);
  // 9. fc2_B + residual(X1) -> out (adaptive dtype)
  gemm_kernel<<<dim3(3, 1024), 256, 0, stream>>>(T2, fc2_Bw, fc2_Bb, X1, d_out,
                                                 192, 96, 192, 1, 1, 0, 0, FLAG);
  scan_kernel<<<1, 256, 0, stream>>>(d_out, 1048576, 2, 10, FLAG);
}

// Round 5
// 3970.714 us; speedup vs baseline: 4.0660x; 4.0660x over previous
//
#include <hip/hip_runtime.h>
#include <hip/hip_bf16.h>

typedef __hip_bfloat16 bf16;

#define N_TOK 65536
#define C_DIM 192
#define PLANE 12582912   // N_TOK * 192 elements (one q/k/v plane)

__device__ __forceinline__ float b2f(bf16 v) { return __bfloat162float(v); }
__device__ __forceinline__ bf16 f2b(float v) { return __float2bfloat16(v); }
// adaptive load of an INPUT tensor element (dtype decided at runtime)
__device__ __forceinline__ float ldA(const void* p, size_t i, int f32) {
  return f32 ? ((const float*)p)[i] : b2f(((const bf16*)p)[i]);
}

// ---------------- dtype detector: bf16-lens exponent statistics (silent) ----------------
__global__ void detect_kernel(const unsigned short* __restrict__ xh, int* __restrict__ flag) {
  if (threadIdx.x == 0) {
    int crazy = 0;
    for (int i = 0; i < 256; ++i) {
      int e = (xh[i] >> 7) & 0xFF;   // bf16 exponent field
      if (e >= 0xF0 || (e >= 1 && e <= 0x60)) ++crazy;
    }
    *flag = (crazy >= 16) ? 1 : 0;   // packed f32 -> ~44% crazy; true bf16 -> ~0
  }
}

// ---------------- LayerNorm: adaptive/bf16 in -> bf16 out; optional window gather ------
__global__ __launch_bounds__(256) void ln_kernel(const void* __restrict__ x,
    const void* __restrict__ g, const void* __restrict__ b, bf16* __restrict__ out,
    int windowize, int xIsBf16Fixed, const int* __restrict__ flag) {
  int wf32 = *flag;
  int f32 = xIsBf16Fixed ? 0 : wf32;
  int token = blockIdx.x * 4 + (threadIdx.x >> 6);
  int lane = threadIdx.x & 63;
  size_t base = (size_t)token * C_DIM;
  float v0 = ldA(x, base + lane, f32);
  float v1 = ldA(x, base + lane + 64, f32);
  float v2 = ldA(x, base + lane + 128, f32);
  float s = v0 + v1 + v2;
  float s2 = v0 * v0 + v1 * v1 + v2 * v2;
  #pragma unroll
  for (int o = 32; o > 0; o >>= 1) { s += __shfl_xor(s, o, 64); s2 += __shfl_xor(s2, o, 64); }
  float mu = s * (1.f / 192.f);
  float var = s2 * (1.f / 192.f) - mu * mu;
  float rstd = rsqrtf(var + 1e-5f);
  int row = token;
  if (windowize) {
    int d = token >> 12, h = (token >> 6) & 63, w = token & 63;
    int win = ((d >> 2) << 6) + ((h >> 3) << 3) + (w >> 3);
    int t = ((d & 3) << 6) + ((h & 7) << 3) + (w & 7);
    row = win * 256 + t;
  }
  bf16* po = out + (size_t)row * C_DIM;
  po[lane]       = f2b((v0 - mu) * rstd * ldA(g, lane, wf32)       + ldA(b, lane, wf32));
  po[lane + 64]  = f2b((v1 - mu) * rstd * ldA(g, lane + 64, wf32)  + ldA(b, lane + 64, wf32));
  po[lane + 128] = f2b((v2 - mu) * rstd * ldA(g, lane + 128, wf32) + ldA(b, lane + 128, wf32));
}

// ---------------- Generic tiled GEMM, f32 accumulate ----------------
// A: M x K intermediate (bf16, or f32 if aF32). B/bias: INPUT weights (adaptive), with
// element offsets boff (B) / biasoff. res: x (adaptive, mode 3) or bf16 X1 (mode 1).
// mode 0: out bf16 = v (+bias)
// mode 1: out (adaptive dtype) = b2f(res) + v + bias     (final output)
// mode 2: qkv scatter into bf16 q/k/v planes (+bias)
// mode 3: out bf16 natural = res(adaptive) + v + bias, window->natural remap (proj)
// mode 4: out f32 += v
__global__ __launch_bounds__(256) void gemm_kernel(const void* __restrict__ Av,
    const void* __restrict__ B, const void* __restrict__ bias,
    const void* __restrict__ res, void* __restrict__ out,
    int Nc, int K, int ldb, int mode, int aF32,
    size_t boff, size_t biasoff, const int* __restrict__ flag) {
  int f32 = *flag;
  __shared__ float As[16][68];
  __shared__ float Bs[16][64];
  int tid = threadIdx.x;
  int tr = tid >> 4, tc = tid & 15;
  int rowBase = blockIdx.y * 64;
  int colBase = blockIdx.x * 64;
  float acc[4][4] = {};
  for (int k0 = 0; k0 < K; k0 += 16) {
    #pragma unroll
    for (int i = 0; i < 4; ++i) {
      int idx = tid + i * 256;
      int m = idx >> 4, kk = idx & 15;
      size_t ai = (size_t)(rowBase + m) * K + (k0 + kk);
      As[kk][m] = aF32 ? ((const float*)Av)[ai] : b2f(((const bf16*)Av)[ai]);
      int kb = idx >> 6, nb = idx & 63;
      int col = colBase + nb;
      Bs[kb][nb] = (col < Nc) ? ldA(B, boff + (size_t)(k0 + kb) * ldb + col, f32) : 0.f;
    }
    __syncthreads();
    #pragma unroll
    for (int kk = 0; kk < 16; ++kk) {
      float a[4], bb[4];
      #pragma unroll
      for (int i = 0; i < 4; ++i) a[i] = As[kk][tr * 4 + i];
      #pragma unroll
      for (int j = 0; j < 4; ++j) bb[j] = Bs[kk][tc * 4 + j];
      #pragma unroll
      for (int i = 0; i < 4; ++i)
        #pragma unroll
        for (int j = 0; j < 4; ++j) acc[i][j] += a[i] * bb[j];
    }
    __syncthreads();
  }
  #pragma unroll
  for (int i = 0; i < 4; ++i) {
    int r = rowBase + tr * 4 + i;
    #pragma unroll
    for (int j = 0; j < 4; ++j) {
      int c = colBase + tc * 4 + j;
      if (c >= Nc) continue;
      float v = acc[i][j];
      if (bias) v += ldA(bias, biasoff + c, f32);
      if (mode == 0) {
        ((bf16*)out)[(size_t)r * Nc + c] = f2b(v);
      } else if (mode == 1) {
        float o = b2f(((const bf16*)res)[(size_t)r * Nc + c]) + v;
        if (f32) ((float*)out)[(size_t)r * Nc + c] = o;
        else     ((bf16*)out)[(size_t)r * Nc + c] = f2b(o);
      } else if (mode == 2) {
        int which = c / 192, rem = c - which * 192;
        int hd = rem >> 5, e = rem & 31;
        int win = r >> 8, t = r & 255;
        ((bf16*)out)[(size_t)which * PLANE +
                     ((size_t)((win * 6 + hd) * 256 + t)) * 32 + e] = f2b(v);
      } else if (mode == 3) {
        int win = r >> 8, t = r & 255;
        int d = ((win >> 6) << 2) + (t >> 6);
        int h = (((win >> 3) & 7) << 3) + ((t >> 3) & 7);
        int w = ((win & 7) << 3) + (t & 7);
        int n = (d << 12) + (h << 6) + w;
        ((bf16*)out)[(size_t)n * C_DIM + c] = f2b(ldA(res, (size_t)n * C_DIM + c, f32) + v);
      } else {  // mode 4: f32 accumulate
        ((float*)out)[(size_t)r * Nc + c] += v;
      }
    }
  }
}

// ---------------- Attention: one block per (win, head), thread per query row -----------
__global__ __launch_bounds__(256) void attn_kernel(const bf16* __restrict__ qkv,
    const void* __restrict__ rel_bias, bf16* __restrict__ out,
    const int* __restrict__ flag) {
  int f32 = *flag;
  __shared__ float sk[256 * 32];
  __shared__ bf16  sv[256 * 32];
  __shared__ float sb[1575];
  __shared__ int   sg[256];
  int head = blockIdx.x;
  int win  = blockIdx.y;
  int wh = win * 6 + head;
  const bf16* qp = qkv + (size_t)wh * 8192;
  const bf16* kp = qkv + PLANE + (size_t)wh * 8192;
  const bf16* vp = qkv + 2 * (size_t)PLANE + (size_t)wh * 8192;
  int tid = threadIdx.x;
  for (int idx = tid; idx < 8192; idx += 256) {
    sk[idx] = b2f(kp[idx]);
    sv[idx] = vp[idx];
  }
  for (int idx = tid; idx < 1575; idx += 256) sb[idx] = ldA(rel_bias, (size_t)idx * 6 + head, f32);
  {
    int t = tid;
    int d = ((win >> 6) << 2) + (t >> 6);
    int h = (((win >> 3) & 7) << 3) + ((t >> 3) & 7);
    int w = ((win & 7) << 3) + (t & 7);
    int d2 = (d + 2) & 15, h2 = (h + 4) & 63, w2 = (w + 4) & 63;
    sg[t] = ((d2 >> 2) << 6) + ((h2 >> 3) << 3) + (w2 >> 3);
  }
  __syncthreads();
  int t = tid;
  float q[32];
  const bf16* qr = qp + t * 32;
  #pragma unroll
  for (int e = 0; e < 32; ++e) q[e] = b2f(qr[e]) * 0.17677669529663687f;
  int td = t >> 6, th = (t >> 3) & 7, tw = t & 7;
  int gt = sg[t];
  float m = 3.0f, l = 0.f;
  float acc[32];
  #pragma unroll
  for (int e = 0; e < 32; ++e) acc[e] = 0.f;
  for (int j = 0; j < 256; ++j) {
    int rel = ((td - (j >> 6) + 3) * 15 + (th - ((j >> 3) & 7) + 7)) * 15 + (tw - (j & 7) + 7);
    float s = sb[rel];
    if (sg[j] != gt) s -= 100.f;
    const float* kr = sk + j * 32;
    float d0 = 0.f, d1 = 0.f, d2 = 0.f, d3 = 0.f;
    #pragma unroll
    for (int e = 0; e < 32; e += 4) {
      d0 += q[e] * kr[e];         d1 += q[e + 1] * kr[e + 1];
      d2 += q[e + 2] * kr[e + 2]; d3 += q[e + 3] * kr[e + 3];
    }
    s += (d0 + d1) + (d2 + d3);
    float p;
    if (s > m) {
      float corr = __expf(m - s);
      l *= corr;
      #pragma unroll
      for (int e = 0; e < 32; ++e) acc[e] *= corr;
      m = s; p = 1.f;
    } else {
      p = __expf(s - m);
    }
    l += p;
    const bf16* vr = sv + j * 32;
    #pragma unroll
    for (int e = 0; e < 32; ++e) acc[e] += p * b2f(vr[e]);
  }
  float inv = 1.f / l;
  bf16* po = out + (size_t)(win * 256 + t) * C_DIM + head * 32;
  #pragma unroll
  for (int e = 0; e < 32; ++e) po[e] = f2b(acc[e] * inv);
}

// ---------------- Depthwise 3x3x3 conv + bias + GELU on a 96-channel chunk -------------
__global__ __launch_bounds__(256) void dwconv_kernel(const bf16* __restrict__ in,
    const void* __restrict__ wgt, const void* __restrict__ wb, bf16* __restrict__ out,
    int cbase, const int* __restrict__ flag) {
  int f32 = *flag;
  int idx = blockIdx.x * 256 + threadIdx.x;   // < 65536*96
  int n = idx / 96, c = idx - n * 96;
  int cg = cbase + c;
  int d = n >> 12, h = (n >> 6) & 63, w = n & 63;
  float s = ldA(wb, cg, f32);
  #pragma unroll
  for (int kd = 0; kd < 3; ++kd) {
    int dd = d + kd - 1;
    if ((unsigned)dd >= 16u) continue;
    #pragma unroll
    for (int kh = 0; kh < 3; ++kh) {
      int hh = h + kh - 1;
      if ((unsigned)hh >= 64u) continue;
      #pragma unroll
      for (int kw = 0; kw < 3; ++kw) {
        int ww = w + kw - 1;
        if ((unsigned)ww >= 64u) continue;
        int nbr = (dd << 12) + (hh << 6) + ww;
        s += b2f(in[(size_t)nbr * 96 + c]) * ldA(wgt, (size_t)cg * 27 + kd * 9 + kh * 3 + kw, f32);
      }
    }
  }
  float gel = 0.5f * s * (1.f + erff(s * 0.70710678118654752f));
  out[(size_t)n * 96 + c] = f2b(gel);
}

// ---------------- zero f32 buffer (float4 granularity) ----------------
__global__ __launch_bounds__(256) void zero_kernel(float4* __restrict__ p) {
  p[(size_t)blockIdx.x * 256 + threadIdx.x] = float4{0.f, 0.f, 0.f, 0.f};
}

extern "C" void kernel_launch(void* const* d_in, const int* in_sizes, int n_in,
                              void* d_out, int out_size, void* d_ws, size_t ws_size,
                              hipStream_t stream) {
  const void* x      = d_in[0];
  const void* n1g    = d_in[1];
  const void* n1b    = d_in[2];
  const void* qkv_w  = d_in[3];
  const void* qkv_b  = d_in[4];
  const void* relb   = d_in[5];
  const void* proj_w = d_in[6];
  const void* proj_b = d_in[7];
  const void* n2g    = d_in[8];
  const void* n2b    = d_in[9];
  const void* fc1_A  = d_in[10];
  const void* fc1_Bw = d_in[11];
  const void* fc1_Bb = d_in[12];
  const void* dw_w   = d_in[13];
  const void* dw_b   = d_in[14];
  const void* fc2_A  = d_in[15];
  const void* fc2_Bw = d_in[16];
  const void* fc2_Bb = d_in[17];

  // ws peak = 120 MiB (+flag at 200 MiB):
  //   [  0, 72): QKV  -> then X1 [0,24) + T1 [24,72)
  //   [ 72, 84): F1 chunk (N x 96 bf16)
  //   [ 84, 96): F2 chunk (N x 96 bf16)
  //   [ 96,120): T2 accumulator (N x 96 f32)
  char* ws = (char*)d_ws;
  bf16* SCR = (bf16*)d_out;                        // H1 / ATT / H2 scratch (24 MiB)
  bf16* QKV = (bf16*)(ws);
  bf16* X1  = (bf16*)(ws);
  bf16* T1  = (bf16*)(ws + (size_t)24 * 1048576);
  bf16* F1c = (bf16*)(ws + (size_t)72 * 1048576);
  bf16* F2c = (bf16*)(ws + (size_t)84 * 1048576);
  float* T2 = (float*)(ws + (size_t)96 * 1048576);
  int* FLAG = (int*)(ws + (size_t)200 * 1048576);

  // 0. dtype detect
  detect_kernel<<<1, 64, 0, stream>>>((const unsigned short*)x, FLAG);
  // 1. LN1 + window gather -> SCR (H1)
  ln_kernel<<<N_TOK / 4, 256, 0, stream>>>(x, n1g, n1b, SCR, 1, 0, FLAG);
  // 2. QKV gemm (window rows), scatter to q/k/v planes
  gemm_kernel<<<dim3(9, 1024), 256, 0, stream>>>(SCR, qkv_w, qkv_b, nullptr, QKV,
                                                 576, 192, 576, 2, 0, 0, 0, FLAG);
  // 3. windowed attention -> SCR (ATT)
  attn_kernel<<<dim3(6, 256), 256, 0, stream>>>(QKV, relb, SCR, FLAG);
  // 4. proj + residual(x), window -> natural -> X1
  gemm_kernel<<<dim3(3, 1024), 256, 0, stream>>>(SCR, proj_w, proj_b, x, X1,
                                                 192, 192, 192, 3, 0, 0, 0, FLAG);
  // 5. LN2 -> SCR (H2)
  ln_kernel<<<N_TOK / 4, 256, 0, stream>>>(X1, n2g, n2b, SCR, 0, 1, FLAG);
  // 6. fc1_A: (N,192)@(192,384) -> T1
  gemm_kernel<<<dim3(6, 1024), 256, 0, stream>>>(SCR, fc1_A, nullptr, nullptr, T1,
                                                 384, 192, 384, 0, 0, 0, 0, FLAG);
  // 7. zero T2
  zero_kernel<<<6144, 256, 0, stream>>>((float4*)T2);
  // 8. MixFFN middle, chunked over HIDDEN in 8 x 96 channels
  for (int k = 0; k < 8; ++k) {
    // 8a. fc1_B chunk: (N,384)@(384,96 cols at 96k)+b -> F1c
    gemm_kernel<<<dim3(2, 1024), 256, 0, stream>>>(T1, fc1_Bw, fc1_Bb, nullptr, F1c,
                                                   96, 384, 768, 0, 0,
                                                   (size_t)96 * k, (size_t)96 * k, FLAG);
    // 8b. depthwise conv + GELU chunk -> F2c
    dwconv_kernel<<<24576, 256, 0, stream>>>(F1c, dw_w, dw_b, F2c, 96 * k, FLAG);
    // 8c. fc2_A chunk: T2 += (N,96)@(rows 96k..96k+96 of fc2_A)
    gemm_kernel<<<dim3(2, 1024), 256, 0, stream>>>(F2c, fc2_A, nullptr, nullptr, T2,
                                                   96, 96, 96, 4, 0,
                                                   (size_t)96 * k * 96, 0, FLAG);
  }
  // 9. fc2_B + residual(X1) -> out (adaptive dtype)
  gemm_kernel<<<dim3(3, 1024), 256, 0, stream>>>(T2, fc2_Bw, fc2_Bb, X1, d_out,
                                                 192, 96, 192, 1, 1, 0, 0, FLAG);
}

// Round 6
// 2468.213 us; speedup vs baseline: 6.5412x; 1.6087x over previous
//
#include <hip/hip_runtime.h>
#include <hip/hip_bf16.h>

typedef __hip_bfloat16 bf16;
typedef __attribute__((ext_vector_type(8))) short short8;
typedef __attribute__((ext_vector_type(4))) float f32x4;

#define N_TOK 65536
#define C_DIM 192
#define PLANE 12582912   // N_TOK * 192 elements (one q/k/v plane)

__device__ __forceinline__ float b2f(bf16 v) { return __bfloat162float(v); }
__device__ __forceinline__ bf16 f2b(float v) { return __float2bfloat16(v); }
// adaptive load of an INPUT tensor element (dtype decided at runtime)
__device__ __forceinline__ float ldA(const void* p, size_t i, int f32) {
  return f32 ? ((const float*)p)[i] : b2f(((const bf16*)p)[i]);
}

// ---------------- dtype detector: bf16-lens exponent statistics (silent) ----------------
__global__ void detect_kernel(const unsigned short* __restrict__ xh, int* __restrict__ flag) {
  if (threadIdx.x == 0) {
    int crazy = 0;
    for (int i = 0; i < 256; ++i) {
      int e = (xh[i] >> 7) & 0xFF;
      if (e >= 0xF0 || (e >= 1 && e <= 0x60)) ++crazy;
    }
    *flag = (crazy >= 16) ? 1 : 0;   // packed f32 -> ~44% crazy; true bf16 -> ~0
  }
}

// ---------------- weight transpose: in (K,N) adaptive -> out (N,K) bf16 ----------------
__global__ __launch_bounds__(256) void transpose_kernel(const void* __restrict__ in,
    bf16* __restrict__ out, int K, int N, const int* __restrict__ flag) {
  int f32 = *flag;
  int idx = blockIdx.x * 256 + threadIdx.x;
  if (idx >= K * N) return;
  int n = idx / K, k = idx - n * K;
  out[idx] = f2b(ldA(in, (size_t)k * N + n, f32));
}

// ---------------- f32 -> bf16 convert ----------------
__global__ __launch_bounds__(256) void cvt_kernel(const float* __restrict__ in,
    bf16* __restrict__ out) {
  int i = blockIdx.x * 256 + threadIdx.x;
  out[i] = f2b(in[i]);
}

// ---------------- zero f32 buffer (float4 granularity) ----------------
__global__ __launch_bounds__(256) void zero_kernel(float4* __restrict__ p) {
  p[(size_t)blockIdx.x * 256 + threadIdx.x] = float4{0.f, 0.f, 0.f, 0.f};
}

// ---------------- LayerNorm: adaptive/bf16 in -> bf16 out; optional window gather ------
__global__ __launch_bounds__(256) void ln_kernel(const void* __restrict__ x,
    const void* __restrict__ g, const void* __restrict__ b, bf16* __restrict__ out,
    int windowize, int xIsBf16Fixed, const int* __restrict__ flag) {
  int wf32 = *flag;
  int f32 = xIsBf16Fixed ? 0 : wf32;
  int token = blockIdx.x * 4 + (threadIdx.x >> 6);
  int lane = threadIdx.x & 63;
  size_t base = (size_t)token * C_DIM;
  float v0 = ldA(x, base + lane, f32);
  float v1 = ldA(x, base + lane + 64, f32);
  float v2 = ldA(x, base + lane + 128, f32);
  float s = v0 + v1 + v2;
  float s2 = v0 * v0 + v1 * v1 + v2 * v2;
  #pragma unroll
  for (int o = 32; o > 0; o >>= 1) { s += __shfl_xor(s, o, 64); s2 += __shfl_xor(s2, o, 64); }
  float mu = s * (1.f / 192.f);
  float var = s2 * (1.f / 192.f) - mu * mu;
  float rstd = rsqrtf(var + 1e-5f);
  int row = token;
  if (windowize) {
    int d = token >> 12, h = (token >> 6) & 63, w = token & 63;
    int win = ((d >> 2) << 6) + ((h >> 3) << 3) + (w >> 3);
    int t = ((d & 3) << 6) + ((h & 7) << 3) + (w & 7);
    row = win * 256 + t;
  }
  bf16* po = out + (size_t)row * C_DIM;
  po[lane]       = f2b((v0 - mu) * rstd * ldA(g, lane, wf32)       + ldA(b, lane, wf32));
  po[lane + 64]  = f2b((v1 - mu) * rstd * ldA(g, lane + 64, wf32)  + ldA(b, lane + 64, wf32));
  po[lane + 128] = f2b((v2 - mu) * rstd * ldA(g, lane + 128, wf32) + ldA(b, lane + 128, wf32));
}

// ---------------- MFMA GEMM: A (M x K bf16) @ BT^T, BT = (N x K bf16) ----------------
// BM=128, BN=64, BK=32; 4 waves 2x2; per wave 64x32 via 4x2 tiles of 16x16x32 MFMA.
// mode 0: out bf16 = v (+bias)
// mode 1: out adaptive = b2f(res bf16) + v + bias      (final output)
// mode 2: qkv scatter into bf16 q/k/v planes (+bias)
// mode 3: out bf16 natural = res(adaptive) + v + bias, window->natural remap (proj)
// mode 4: out f32 += v
__global__ __launch_bounds__(256) void mfma_gemm(const bf16* __restrict__ A,
    const bf16* __restrict__ BT, const void* __restrict__ bias,
    const void* __restrict__ res, void* __restrict__ out,
    int Nc, int K, int ldk, int koff, int mode, size_t biasoff,
    const int* __restrict__ flag) {
  int f32 = *flag;
  __shared__ short As[128 * 40];   // pad 32->40: 2-way max on b128 reads
  __shared__ short Bs[64 * 40];
  int tid = threadIdx.x;
  int wave = tid >> 6, lane = tid & 63;
  int wm = wave >> 1, wn = wave & 1;
  int lr = lane & 15, quad = lane >> 4;
  int rowBase = blockIdx.y * 128;
  int colBase = blockIdx.x * 64;
  f32x4 acc[4][2];
  #pragma unroll
  for (int i = 0; i < 4; ++i)
    #pragma unroll
    for (int j = 0; j < 2; ++j) acc[i][j] = f32x4{0.f, 0.f, 0.f, 0.f};

  for (int k0 = 0; k0 < K; k0 += 32) {
    // stage A tile: 128 rows x 32 k (2 x 256 threads x 8 bf16)
    #pragma unroll
    for (int it = 0; it < 2; ++it) {
      int idx = tid + it * 256;
      int row = idx >> 2, kc = (idx & 3) * 8;
      uint4 v = *(const uint4*)(A + (size_t)(rowBase + row) * K + k0 + kc);
      *(uint4*)&As[row * 40 + kc] = v;
    }
    // stage B tile: 64 n-rows x 32 k
    {
      int n = tid >> 2, kc = (tid & 3) * 8;
      uint4 v = uint4{0u, 0u, 0u, 0u};
      if (colBase + n < Nc)
        v = *(const uint4*)(BT + (size_t)(colBase + n) * ldk + koff + k0 + kc);
      *(uint4*)&Bs[n * 40 + kc] = v;
    }
    __syncthreads();
    short8 af[4], bf[2];
    #pragma unroll
    for (int i = 0; i < 4; ++i)
      af[i] = *(const short8*)&As[(wm * 64 + i * 16 + lr) * 40 + quad * 8];
    #pragma unroll
    for (int j = 0; j < 2; ++j)
      bf[j] = *(const short8*)&Bs[(wn * 32 + j * 16 + lr) * 40 + quad * 8];
    #pragma unroll
    for (int i = 0; i < 4; ++i)
      #pragma unroll
      for (int j = 0; j < 2; ++j)
        acc[i][j] = __builtin_amdgcn_mfma_f32_16x16x32_bf16(af[i], bf[j], acc[i][j], 0, 0, 0);
    __syncthreads();
  }

  // epilogue: C row = quad*4 + r, col = lr (within 16x16 tile)
  #pragma unroll
  for (int i = 0; i < 4; ++i) {
    #pragma unroll
    for (int j = 0; j < 2; ++j) {
      #pragma unroll
      for (int r = 0; r < 4; ++r) {
        int row = rowBase + wm * 64 + i * 16 + quad * 4 + r;
        int c = colBase + wn * 32 + j * 16 + lr;
        if (c >= Nc) continue;
        float v = acc[i][j][r];
        if (bias) v += ldA(bias, biasoff + c, f32);
        if (mode == 0) {
          ((bf16*)out)[(size_t)row * Nc + c] = f2b(v);
        } else if (mode == 1) {
          float o = b2f(((const bf16*)res)[(size_t)row * Nc + c]) + v;
          if (f32) ((float*)out)[(size_t)row * Nc + c] = o;
          else     ((bf16*)out)[(size_t)row * Nc + c] = f2b(o);
        } else if (mode == 2) {
          int which = c / 192, rem = c - which * 192;
          int hd = rem >> 5, e = rem & 31;
          int win = row >> 8, t = row & 255;
          ((bf16*)out)[(size_t)which * PLANE +
                       ((size_t)((win * 6 + hd) * 256 + t)) * 32 + e] = f2b(v);
        } else if (mode == 3) {
          int win = row >> 8, t = row & 255;
          int d = ((win >> 6) << 2) + (t >> 6);
          int h = (((win >> 3) & 7) << 3) + ((t >> 3) & 7);
          int w = ((win & 7) << 3) + (t & 7);
          int n = (d << 12) + (h << 6) + w;
          ((bf16*)out)[(size_t)n * C_DIM + c] = f2b(ldA(res, (size_t)n * C_DIM + c, f32) + v);
        } else {  // mode 4: f32 accumulate
          ((float*)out)[(size_t)row * Nc + c] += v;
        }
      }
    }
  }
}

// ---------------- Attention: one block per (win, head), thread per query row -----------
__global__ __launch_bounds__(256) void attn_kernel(const bf16* __restrict__ qkv,
    const void* __restrict__ rel_bias, bf16* __restrict__ out,
    const int* __restrict__ flag) {
  int f32 = *flag;
  __shared__ float sk[256 * 32];
  __shared__ bf16  sv[256 * 32];
  __shared__ float sb[1575];
  __shared__ int   sg[256];
  int head = blockIdx.x;
  int win  = blockIdx.y;
  int wh = win * 6 + head;
  const bf16* qp = qkv + (size_t)wh * 8192;
  const bf16* kp = qkv + PLANE + (size_t)wh * 8192;
  const bf16* vp = qkv + 2 * (size_t)PLANE + (size_t)wh * 8192;
  int tid = threadIdx.x;
  for (int idx = tid; idx < 8192; idx += 256) {
    sk[idx] = b2f(kp[idx]);
    sv[idx] = vp[idx];
  }
  for (int idx = tid; idx < 1575; idx += 256) sb[idx] = ldA(rel_bias, (size_t)idx * 6 + head, f32);
  {
    int t = tid;
    int d = ((win >> 6) << 2) + (t >> 6);
    int h = (((win >> 3) & 7) << 3) + ((t >> 3) & 7);
    int w = ((win & 7) << 3) + (t & 7);
    int d2 = (d + 2) & 15, h2 = (h + 4) & 63, w2 = (w + 4) & 63;
    sg[t] = ((d2 >> 2) << 6) + ((h2 >> 3) << 3) + (w2 >> 3);
  }
  __syncthreads();
  int t = tid;
  float q[32];
  const bf16* qr = qp + t * 32;
  #pragma unroll
  for (int e = 0; e < 32; ++e) q[e] = b2f(qr[e]) * 0.17677669529663687f;
  int td = t >> 6, th = (t >> 3) & 7, tw = t & 7;
  int gt = sg[t];
  float m = 3.0f, l = 0.f;
  float acc[32];
  #pragma unroll
  for (int e = 0; e < 32; ++e) acc[e] = 0.f;
  for (int j = 0; j < 256; ++j) {
    int rel = ((td - (j >> 6) + 3) * 15 + (th - ((j >> 3) & 7) + 7)) * 15 + (tw - (j & 7) + 7);
    float s = sb[rel];
    if (sg[j] != gt) s -= 100.f;
    const float* kr = sk + j * 32;
    float d0 = 0.f, d1 = 0.f, d2 = 0.f, d3 = 0.f;
    #pragma unroll
    for (int e = 0; e < 32; e += 4) {
      d0 += q[e] * kr[e];         d1 += q[e + 1] * kr[e + 1];
      d2 += q[e + 2] * kr[e + 2]; d3 += q[e + 3] * kr[e + 3];
    }
    s += (d0 + d1) + (d2 + d3);
    float p;
    if (s > m) {
      float corr = __expf(m - s);
      l *= corr;
      #pragma unroll
      for (int e = 0; e < 32; ++e) acc[e] *= corr;
      m = s; p = 1.f;
    } else {
      p = __expf(s - m);
    }
    l += p;
    const bf16* vr = sv + j * 32;
    #pragma unroll
    for (int e = 0; e < 32; ++e) acc[e] += p * b2f(vr[e]);
  }
  float inv = 1.f / l;
  bf16* po = out + (size_t)(win * 256 + t) * C_DIM + head * 32;
  #pragma unroll
  for (int e = 0; e < 32; ++e) po[e] = f2b(acc[e] * inv);
}

// ---------------- Depthwise 3x3x3 conv + bias + GELU on a 192-channel chunk ------------
__global__ __launch_bounds__(256) void dwconv_kernel(const bf16* __restrict__ in,
    const void* __restrict__ wgt, const void* __restrict__ wb, bf16* __restrict__ out,
    int cbase, const int* __restrict__ flag) {
  int f32 = *flag;
  int idx = blockIdx.x * 256 + threadIdx.x;   // < 65536*192
  int n = idx / 192, c = idx - n * 192;
  int cg = cbase + c;
  int d = n >> 12, h = (n >> 6) & 63, w = n & 63;
  float s = ldA(wb, cg, f32);
  #pragma unroll
  for (int kd = 0; kd < 3; ++kd) {
    int dd = d + kd - 1;
    if ((unsigned)dd >= 16u) continue;
    #pragma unroll
    for (int kh = 0; kh < 3; ++kh) {
      int hh = h + kh - 1;
      if ((unsigned)hh >= 64u) continue;
      #pragma unroll
      for (int kw = 0; kw < 3; ++kw) {
        int ww = w + kw - 1;
        if ((unsigned)ww >= 64u) continue;
        int nbr = (dd << 12) + (hh << 6) + ww;
        s += b2f(in[(size_t)nbr * 192 + c]) * ldA(wgt, (size_t)cg * 27 + kd * 9 + kh * 3 + kw, f32);
      }
    }
  }
  float gel = 0.5f * s * (1.f + erff(s * 0.70710678118654752f));
  out[(size_t)n * 192 + c] = f2b(gel);
}

extern "C" void kernel_launch(void* const* d_in, const int* in_sizes, int n_in,
                              void* d_out, int out_size, void* d_ws, size_t ws_size,
                              hipStream_t stream) {
  const void* x      = d_in[0];
  const void* n1g    = d_in[1];
  const void* n1b    = d_in[2];
  const void* qkv_w  = d_in[3];
  const void* qkv_b  = d_in[4];
  const void* relb   = d_in[5];
  const void* proj_w = d_in[6];
  const void* proj_b = d_in[7];
  const void* n2g    = d_in[8];
  const void* n2b    = d_in[9];
  const void* fc1_A  = d_in[10];
  const void* fc1_Bw = d_in[11];
  const void* fc1_Bb = d_in[12];
  const void* dw_w   = d_in[13];
  const void* dw_b   = d_in[14];
  const void* fc2_A  = d_in[15];
  const void* fc2_Bw = d_in[16];
  const void* fc2_Bb = d_in[17];

  // ws layout (MiB):
  //  [  0, 72): QKV planes -> later X1 [0,24) + T1 [24,72)
  //  [ 72, 96): F1c (N x 192 bf16)
  //  [ 96,120): F2c (N x 192 bf16)
  //  [120,144): T2  (N x 96 f32)
  //  [144,156): T2bf (N x 96 bf16)
  //  [160,166): transposed weights (bf16)
  //  [200]    : FLAG
  char* ws = (char*)d_ws;
  bf16* SCR  = (bf16*)d_out;                         // H1 / ATT / H2 scratch
  bf16* QKV  = (bf16*)(ws);
  bf16* X1   = (bf16*)(ws);
  bf16* T1   = (bf16*)(ws + (size_t)24 * 1048576);
  bf16* F1c  = (bf16*)(ws + (size_t)72 * 1048576);
  bf16* F2c  = (bf16*)(ws + (size_t)96 * 1048576);
  float* T2  = (float*)(ws + (size_t)120 * 1048576);
  bf16* T2bf = (bf16*)(ws + (size_t)144 * 1048576);
  bf16* QKVT  = (bf16*)(ws + (size_t)160 * 1048576); // (576,192)
  bf16* PROJT = (bf16*)(ws + (size_t)161 * 1048576); // (192,192)
  bf16* FC1AT = (bf16*)(ws + (size_t)162 * 1048576); // (384,192)
  bf16* FC1BT = (bf16*)(ws + (size_t)163 * 1048576); // (768,384)
  bf16* FC2AT = (bf16*)(ws + (size_t)165 * 1048576); // (96,768)
  bf16* FC2BT = (bf16*)(ws + (size_t)166 * 1048576); // (192,96)
  int* FLAG   = (int*)(ws + (size_t)200 * 1048576);

  // 0. dtype detect + weight transposes
  detect_kernel<<<1, 64, 0, stream>>>((const unsigned short*)x, FLAG);
  transpose_kernel<<<432, 256, 0, stream>>>(qkv_w, QKVT, 192, 576, FLAG);
  transpose_kernel<<<144, 256, 0, stream>>>(proj_w, PROJT, 192, 192, FLAG);
  transpose_kernel<<<288, 256, 0, stream>>>(fc1_A, FC1AT, 192, 384, FLAG);
  transpose_kernel<<<1152, 256, 0, stream>>>(fc1_Bw, FC1BT, 384, 768, FLAG);
  transpose_kernel<<<288, 256, 0, stream>>>(fc2_A, FC2AT, 768, 96, FLAG);
  transpose_kernel<<<72, 256, 0, stream>>>(fc2_Bw, FC2BT, 96, 192, FLAG);
  // 1. LN1 + window gather -> SCR (H1)
  ln_kernel<<<N_TOK / 4, 256, 0, stream>>>(x, n1g, n1b, SCR, 1, 0, FLAG);
  // 2. QKV gemm (window rows), scatter to q/k/v planes
  mfma_gemm<<<dim3(9, 512), 256, 0, stream>>>(SCR, QKVT, qkv_b, nullptr, QKV,
                                              576, 192, 192, 0, 2, 0, FLAG);
  // 3. windowed attention -> SCR (ATT)
  attn_kernel<<<dim3(6, 256), 256, 0, stream>>>(QKV, relb, SCR, FLAG);
  // 4. proj + residual(x), window -> natural -> X1
  mfma_gemm<<<dim3(3, 512), 256, 0, stream>>>(SCR, PROJT, proj_b, x, X1,
                                              192, 192, 192, 0, 3, 0, FLAG);
  // 5. LN2 -> SCR (H2)
  ln_kernel<<<N_TOK / 4, 256, 0, stream>>>(X1, n2g, n2b, SCR, 0, 1, FLAG);
  // 6. fc1_A: (N,192)@(192,384) -> T1
  mfma_gemm<<<dim3(6, 512), 256, 0, stream>>>(SCR, FC1AT, nullptr, nullptr, T1,
                                              384, 192, 192, 0, 0, 0, FLAG);
  // 7. zero T2
  zero_kernel<<<6144, 256, 0, stream>>>((float4*)T2);
  // 8. MixFFN middle, chunked over HIDDEN in 4 x 192 channels
  for (int k = 0; k < 4; ++k) {
    // 8a. fc1_B chunk: (N,384)@(384,cols 192k..)+b -> F1c
    mfma_gemm<<<dim3(3, 512), 256, 0, stream>>>(T1, FC1BT + (size_t)192 * k * 384,
                                                fc1_Bb, nullptr, F1c,
                                                192, 384, 384, 0, 0, (size_t)192 * k, FLAG);
    // 8b. depthwise conv + GELU chunk -> F2c
    dwconv_kernel<<<49152, 256, 0, stream>>>(F1c, dw_w, dw_b, F2c, 192 * k, FLAG);
    // 8c. fc2_A chunk: T2 += (N,192)@(rows 192k.. of fc2_A)
    mfma_gemm<<<dim3(2, 512), 256, 0, stream>>>(F2c, FC2AT, nullptr, nullptr, T2,
                                                96, 192, 768, 192 * k, 4, 0, FLAG);
  }
  // 9. convert T2 -> bf16
  cvt_kernel<<<24576, 256, 0, stream>>>(T2, T2bf);
  // 10. fc2_B + residual(X1) -> out (adaptive dtype)
  mfma_gemm<<<dim3(3, 512), 256, 0, stream>>>(T2bf, FC2BT, fc2_Bb, X1, d_out,
                                              192, 96, 96, 0, 1, 0, FLAG);
}

// Round 7
// 1073.778 us; speedup vs baseline: 15.0357x; 2.2986x over previous
//
#include <hip/hip_runtime.h>
#include <hip/hip_bf16.h>

typedef __hip_bfloat16 bf16;
typedef __attribute__((ext_vector_type(8))) short short8;
typedef __attribute__((ext_vector_type(4))) float f32x4;

#define N_TOK 65536
#define C_DIM 192
#define PLANE 12582912   // N_TOK * 192 elements (one q/k/v plane)
#define SCALE 0.17677669529663687f

__device__ __forceinline__ float b2f(bf16 v) { return __bfloat162float(v); }
__device__ __forceinline__ bf16 f2b(float v) { return __float2bfloat16(v); }
__device__ __forceinline__ float ldA(const void* p, size_t i, int f32) {
  return f32 ? ((const float*)p)[i] : b2f(((const bf16*)p)[i]);
}
__device__ __forceinline__ float s2f(short s) { union { short s; bf16 b; } u; u.s = s; return b2f(u.b); }

// ---------------- dtype detector (silent) ----------------
__global__ void detect_kernel(const unsigned short* __restrict__ xh, int* __restrict__ flag) {
  if (threadIdx.x == 0) {
    int crazy = 0;
    for (int i = 0; i < 256; ++i) {
      int e = (xh[i] >> 7) & 0xFF;
      if (e >= 0xF0 || (e >= 1 && e <= 0x60)) ++crazy;
    }
    *flag = (crazy >= 16) ? 1 : 0;
  }
}

// ---------------- weight transpose: in (K,N) adaptive -> out (N,K) bf16 ----------------
__global__ __launch_bounds__(256) void transpose_kernel(const void* __restrict__ in,
    bf16* __restrict__ out, int K, int N, const int* __restrict__ flag) {
  int f32 = *flag;
  int idx = blockIdx.x * 256 + threadIdx.x;
  if (idx >= K * N) return;
  int n = idx / K, k = idx - n * K;
  out[idx] = f2b(ldA(in, (size_t)k * N + n, f32));
}

// ---------------- dw weight transpose: (768,27) adaptive -> (27,768) bf16 ----------------
__global__ __launch_bounds__(256) void dwT_kernel(const void* __restrict__ in,
    bf16* __restrict__ out, const int* __restrict__ flag) {
  int f32 = *flag;
  int idx = blockIdx.x * 256 + threadIdx.x;
  if (idx >= 27 * 768) return;
  int tap = idx / 768, c = idx - tap * 768;
  out[idx] = f2b(ldA(in, (size_t)c * 27 + tap, f32));
}

// ---------------- f32 -> bf16 convert ----------------
__global__ __launch_bounds__(256) void cvt_kernel(const float* __restrict__ in,
    bf16* __restrict__ out) {
  int i = blockIdx.x * 256 + threadIdx.x;
  out[i] = f2b(in[i]);
}

// ---------------- zero f32 buffer ----------------
__global__ __launch_bounds__(256) void zero_kernel(float4* __restrict__ p) {
  p[(size_t)blockIdx.x * 256 + threadIdx.x] = float4{0.f, 0.f, 0.f, 0.f};
}

// ---------------- LayerNorm ----------------
__global__ __launch_bounds__(256) void ln_kernel(const void* __restrict__ x,
    const void* __restrict__ g, const void* __restrict__ b, bf16* __restrict__ out,
    int windowize, int xIsBf16Fixed, const int* __restrict__ flag) {
  int wf32 = *flag;
  int f32 = xIsBf16Fixed ? 0 : wf32;
  int token = blockIdx.x * 4 + (threadIdx.x >> 6);
  int lane = threadIdx.x & 63;
  size_t base = (size_t)token * C_DIM;
  float v0 = ldA(x, base + lane, f32);
  float v1 = ldA(x, base + lane + 64, f32);
  float v2 = ldA(x, base + lane + 128, f32);
  float s = v0 + v1 + v2;
  float s2 = v0 * v0 + v1 * v1 + v2 * v2;
  #pragma unroll
  for (int o = 32; o > 0; o >>= 1) { s += __shfl_xor(s, o, 64); s2 += __shfl_xor(s2, o, 64); }
  float mu = s * (1.f / 192.f);
  float var = s2 * (1.f / 192.f) - mu * mu;
  float rstd = rsqrtf(var + 1e-5f);
  int row = token;
  if (windowize) {
    int d = token >> 12, h = (token >> 6) & 63, w = token & 63;
    int win = ((d >> 2) << 6) + ((h >> 3) << 3) + (w >> 3);
    int t = ((d & 3) << 6) + ((h & 7) << 3) + (w & 7);
    row = win * 256 + t;
  }
  bf16* po = out + (size_t)row * C_DIM;
  po[lane]       = f2b((v0 - mu) * rstd * ldA(g, lane, wf32)       + ldA(b, lane, wf32));
  po[lane + 64]  = f2b((v1 - mu) * rstd * ldA(g, lane + 64, wf32)  + ldA(b, lane + 64, wf32));
  po[lane + 128] = f2b((v2 - mu) * rstd * ldA(g, lane + 128, wf32) + ldA(b, lane + 128, wf32));
}

// ---------------- MFMA GEMM (as round 6) ----------------
__global__ __launch_bounds__(256) void mfma_gemm(const bf16* __restrict__ A,
    const bf16* __restrict__ BT, const void* __restrict__ bias,
    const void* __restrict__ res, void* __restrict__ out,
    int Nc, int K, int ldk, int koff, int mode, size_t biasoff,
    const int* __restrict__ flag) {
  int f32 = *flag;
  __shared__ short As[128 * 40];
  __shared__ short Bs[64 * 40];
  int tid = threadIdx.x;
  int wave = tid >> 6, lane = tid & 63;
  int wm = wave >> 1, wn = wave & 1;
  int lr = lane & 15, quad = lane >> 4;
  int rowBase = blockIdx.y * 128;
  int colBase = blockIdx.x * 64;
  f32x4 acc[4][2];
  #pragma unroll
  for (int i = 0; i < 4; ++i)
    #pragma unroll
    for (int j = 0; j < 2; ++j) acc[i][j] = f32x4{0.f, 0.f, 0.f, 0.f};

  for (int k0 = 0; k0 < K; k0 += 32) {
    #pragma unroll
    for (int it = 0; it < 2; ++it) {
      int idx = tid + it * 256;
      int row = idx >> 2, kc = (idx & 3) * 8;
      uint4 v = *(const uint4*)(A + (size_t)(rowBase + row) * K + k0 + kc);
      *(uint4*)&As[row * 40 + kc] = v;
    }
    {
      int n = tid >> 2, kc = (tid & 3) * 8;
      uint4 v = uint4{0u, 0u, 0u, 0u};
      if (colBase + n < Nc)
        v = *(const uint4*)(BT + (size_t)(colBase + n) * ldk + koff + k0 + kc);
      *(uint4*)&Bs[n * 40 + kc] = v;
    }
    __syncthreads();
    short8 af[4], bf[2];
    #pragma unroll
    for (int i = 0; i < 4; ++i)
      af[i] = *(const short8*)&As[(wm * 64 + i * 16 + lr) * 40 + quad * 8];
    #pragma unroll
    for (int j = 0; j < 2; ++j)
      bf[j] = *(const short8*)&Bs[(wn * 32 + j * 16 + lr) * 40 + quad * 8];
    #pragma unroll
    for (int i = 0; i < 4; ++i)
      #pragma unroll
      for (int j = 0; j < 2; ++j)
        acc[i][j] = __builtin_amdgcn_mfma_f32_16x16x32_bf16(af[i], bf[j], acc[i][j], 0, 0, 0);
    __syncthreads();
  }

  #pragma unroll
  for (int i = 0; i < 4; ++i) {
    #pragma unroll
    for (int j = 0; j < 2; ++j) {
      #pragma unroll
      for (int r = 0; r < 4; ++r) {
        int row = rowBase + wm * 64 + i * 16 + quad * 4 + r;
        int c = colBase + wn * 32 + j * 16 + lr;
        if (c >= Nc) continue;
        float v = acc[i][j][r];
        if (bias) v += ldA(bias, biasoff + c, f32);
        if (mode == 0) {
          ((bf16*)out)[(size_t)row * Nc + c] = f2b(v);
        } else if (mode == 1) {
          float o = b2f(((const bf16*)res)[(size_t)row * Nc + c]) + v;
          if (f32) ((float*)out)[(size_t)row * Nc + c] = o;
          else     ((bf16*)out)[(size_t)row * Nc + c] = f2b(o);
        } else if (mode == 2) {
          int which = c / 192, rem = c - which * 192;
          int hd = rem >> 5, e = rem & 31;
          int win = row >> 8, t = row & 255;
          ((bf16*)out)[(size_t)which * PLANE +
                       ((size_t)((win * 6 + hd) * 256 + t)) * 32 + e] = f2b(v);
        } else if (mode == 3) {
          int win = row >> 8, t = row & 255;
          int d = ((win >> 6) << 2) + (t >> 6);
          int h = (((win >> 3) & 7) << 3) + ((t >> 3) & 7);
          int w = ((win & 7) << 3) + (t & 7);
          int n = (d << 12) + (h << 6) + w;
          ((bf16*)out)[(size_t)n * C_DIM + c] = f2b(ldA(res, (size_t)n * C_DIM + c, f32) + v);
        } else {
          ((float*)out)[(size_t)row * Nc + c] += v;
        }
      }
    }
  }
}

// ---------------- MFMA attention: block per (win, head), 4 waves x 64 q-rows ----------
__global__ __launch_bounds__(256) void attn_mfma_kernel(const bf16* __restrict__ qkv,
    const void* __restrict__ rel_bias, bf16* __restrict__ out,
    const int* __restrict__ flag) {
  int f32 = *flag;
  __shared__ bf16 sK[256 * 40];     // K tokens x 32 hd, stride 40 (80B, 16B-aligned)
  __shared__ bf16 sVT[32 * 264];    // V^T: hd x token, stride 264 (528B)
  __shared__ bf16 sP[4][64 * 40];   // per-wave P chunk (64 x 32)
  __shared__ float sb[1575];        // per-head rel bias
  __shared__ int  sgb[256];         // (group<<12) | base(t)
  int head = blockIdx.x, win = blockIdx.y;
  int wh = win * 6 + head;
  const bf16* qp = qkv + (size_t)wh * 8192;
  const bf16* kp = qkv + PLANE + (size_t)wh * 8192;
  const bf16* vp = qkv + 2 * (size_t)PLANE + (size_t)wh * 8192;
  int tid = threadIdx.x;
  int wave = tid >> 6, lane = tid & 63;
  int lr = lane & 15, quad = lane >> 4;

  // stage K (vector)
  #pragma unroll
  for (int it = 0; it < 4; ++it) {
    int idx = tid + it * 256;              // 0..1023
    int tok = idx >> 2, kc = (idx & 3) * 8;
    uint4 v = *(const uint4*)(kp + tok * 32 + kc);
    *(uint4*)&sK[tok * 40 + kc] = v;
  }
  // stage V^T (scalar transpose, one-time)
  for (int idx = tid; idx < 8192; idx += 256) {
    int tok = idx >> 5, hd = idx & 31;
    sVT[hd * 264 + tok] = vp[tok * 32 + hd];
  }
  for (int idx = tid; idx < 1575; idx += 256) sb[idx] = ldA(rel_bias, (size_t)idx * 6 + head, f32);
  {
    int t = tid & 255;
    int d = ((win >> 6) << 2) + (t >> 6);
    int h = (((win >> 3) & 7) << 3) + ((t >> 3) & 7);
    int w = ((win & 7) << 3) + (t & 7);
    int d2 = (d + 2) & 15, h2 = (h + 4) & 63, w2 = (w + 4) & 63;
    int g = ((d2 >> 2) << 6) + ((h2 >> 3) << 3) + (w2 >> 3);
    int td = t >> 6, th = (t >> 3) & 7, tw = t & 7;
    int base = (td * 15 + th) * 15 + tw;
    sgb[t] = (g << 12) | base;
  }
  __syncthreads();

  int wm = wave * 64;
  // Q A-fragments straight from global (one-time, L2-served)
  short8 aq[4];
  #pragma unroll
  for (int i = 0; i < 4; ++i)
    aq[i] = *(const short8*)(qp + (wm + i * 16 + lr) * 32 + quad * 8);
  int rinfo[16];
  #pragma unroll
  for (int i = 0; i < 4; ++i)
    #pragma unroll
    for (int r = 0; r < 4; ++r)
      rinfo[i * 4 + r] = sgb[wm + i * 16 + quad * 4 + r];

  f32x4 acc_o[4][2], acc_l[4];
  #pragma unroll
  for (int i = 0; i < 4; ++i) {
    acc_l[i] = f32x4{0.f, 0.f, 0.f, 0.f};
    #pragma unroll
    for (int j = 0; j < 2; ++j) acc_o[i][j] = f32x4{0.f, 0.f, 0.f, 0.f};
  }
  // ones B-fragment: column 0 = 1.0 -> row sums via MFMA
  short8 bones;
  #pragma unroll
  for (int j = 0; j < 8; ++j) bones[j] = (lr == 0) ? (short)0x3F80 : (short)0;

  for (int c = 0; c < 8; ++c) {
    short8 bk[2];
    #pragma unroll
    for (int jt = 0; jt < 2; ++jt)
      bk[jt] = *(const short8*)&sK[(c * 32 + jt * 16 + lr) * 40 + quad * 8];
    f32x4 s[4][2];
    #pragma unroll
    for (int i = 0; i < 4; ++i)
      #pragma unroll
      for (int jt = 0; jt < 2; ++jt) {
        s[i][jt] = f32x4{0.f, 0.f, 0.f, 0.f};
        s[i][jt] = __builtin_amdgcn_mfma_f32_16x16x32_bf16(aq[i], bk[jt], s[i][jt], 0, 0, 0);
      }
    int cinfo[2];
    #pragma unroll
    for (int jt = 0; jt < 2; ++jt) cinfo[jt] = sgb[c * 32 + jt * 16 + lr];
    #pragma unroll
    for (int i = 0; i < 4; ++i)
      #pragma unroll
      for (int jt = 0; jt < 2; ++jt)
        #pragma unroll
        for (int r = 0; r < 4; ++r) {
          int ri = rinfo[i * 4 + r], ci = cinfo[jt];
          float sc = s[i][jt][r] * SCALE + sb[(ri & 0xFFF) - (ci & 0xFFF) + 787];
          float p = ((ri >> 12) == (ci >> 12)) ? __expf(sc) : 0.f;
          sP[wave][(i * 16 + quad * 4 + r) * 40 + jt * 16 + lr] = f2b(p);
        }
    // wave-private LDS roundtrip (no barrier needed)
    short8 ap[4];
    #pragma unroll
    for (int i = 0; i < 4; ++i)
      ap[i] = *(const short8*)&sP[wave][(i * 16 + lr) * 40 + quad * 8];
    short8 bv[2];
    #pragma unroll
    for (int jh = 0; jh < 2; ++jh)
      bv[jh] = *(const short8*)&sVT[(jh * 16 + lr) * 264 + c * 32 + quad * 8];
    #pragma unroll
    for (int i = 0; i < 4; ++i) {
      #pragma unroll
      for (int jh = 0; jh < 2; ++jh)
        acc_o[i][jh] = __builtin_amdgcn_mfma_f32_16x16x32_bf16(ap[i], bv[jh], acc_o[i][jh], 0, 0, 0);
      acc_l[i] = __builtin_amdgcn_mfma_f32_16x16x32_bf16(ap[i], bones, acc_l[i], 0, 0, 0);
    }
  }
  // normalize + store
  #pragma unroll
  for (int i = 0; i < 4; ++i) {
    #pragma unroll
    for (int r = 0; r < 4; ++r) {
      float l = __shfl(acc_l[i][r], lane & 48, 64);   // row-sum lives in lr==0 lane of quad
      float inv = 1.f / l;
      int t = wm + i * 16 + quad * 4 + r;
      bf16* po = out + (size_t)(win * 256 + t) * C_DIM + head * 32;
      po[lr]      = f2b(acc_o[i][0][r] * inv);
      po[16 + lr] = f2b(acc_o[i][1][r] * inv);
    }
  }
}

// ---------------- Depthwise conv + GELU, 8 channels per thread ----------------
__global__ __launch_bounds__(256) void dwconv8_kernel(const bf16* __restrict__ in,
    const bf16* __restrict__ wT, const void* __restrict__ wb, bf16* __restrict__ out,
    int cbase, const int* __restrict__ flag) {
  int f32 = *flag;
  int idx = blockIdx.x * 256 + threadIdx.x;   // 65536 * 24
  int n = idx / 24, g = idx - n * 24;
  int c0 = g * 8;
  int d = n >> 12, h = (n >> 6) & 63, w = n & 63;
  float acc[8];
  #pragma unroll
  for (int e = 0; e < 8; ++e) acc[e] = ldA(wb, cbase + c0 + e, f32);
  #pragma unroll
  for (int kd = 0; kd < 3; ++kd) {
    int dd = d + kd - 1;
    if ((unsigned)dd >= 16u) continue;
    #pragma unroll
    for (int kh = 0; kh < 3; ++kh) {
      int hh = h + kh - 1;
      if ((unsigned)hh >= 64u) continue;
      #pragma unroll
      for (int kw = 0; kw < 3; ++kw) {
        int ww = w + kw - 1;
        if ((unsigned)ww >= 64u) continue;
        int nbr = (dd << 12) + (hh << 6) + ww;
        int tap = kd * 9 + kh * 3 + kw;
        short8 xv = *(const short8*)(in + (size_t)nbr * 192 + c0);
        short8 wv = *(const short8*)(wT + tap * 768 + cbase + c0);
        #pragma unroll
        for (int e = 0; e < 8; ++e) acc[e] += s2f(xv[e]) * s2f(wv[e]);
      }
    }
  }
  bf16* po = out + (size_t)n * 192 + c0;
  #pragma unroll
  for (int e = 0; e < 8; ++e) {
    float s = acc[e];
    po[e] = f2b(0.5f * s * (1.f + erff(s * 0.70710678118654752f)));
  }
}

extern "C" void kernel_launch(void* const* d_in, const int* in_sizes, int n_in,
                              void* d_out, int out_size, void* d_ws, size_t ws_size,
                              hipStream_t stream) {
  const void* x      = d_in[0];
  const void* n1g    = d_in[1];
  const void* n1b    = d_in[2];
  const void* qkv_w  = d_in[3];
  const void* qkv_b  = d_in[4];
  const void* relb   = d_in[5];
  const void* proj_w = d_in[6];
  const void* proj_b = d_in[7];
  const void* n2g    = d_in[8];
  const void* n2b    = d_in[9];
  const void* fc1_A  = d_in[10];
  const void* fc1_Bw = d_in[11];
  const void* fc1_Bb = d_in[12];
  const void* dw_w   = d_in[13];
  const void* dw_b   = d_in[14];
  const void* fc2_A  = d_in[15];
  const void* fc2_Bw = d_in[16];
  const void* fc2_Bb = d_in[17];

  char* ws = (char*)d_ws;
  bf16* SCR  = (bf16*)d_out;                         // H1 / ATT / H2 scratch
  bf16* QKV  = (bf16*)(ws);
  bf16* X1   = (bf16*)(ws);
  bf16* T1   = (bf16*)(ws + (size_t)24 * 1048576);
  bf16* F1c  = (bf16*)(ws + (size_t)72 * 1048576);
  bf16* F2c  = (bf16*)(ws + (size_t)96 * 1048576);
  float* T2  = (float*)(ws + (size_t)120 * 1048576);
  bf16* T2bf = (bf16*)(ws + (size_t)144 * 1048576);
  bf16* QKVT  = (bf16*)(ws + (size_t)160 * 1048576); // (576,192)
  bf16* PROJT = (bf16*)(ws + (size_t)161 * 1048576); // (192,192)
  bf16* FC1AT = (bf16*)(ws + (size_t)162 * 1048576); // (384,192)
  bf16* FC1BT = (bf16*)(ws + (size_t)163 * 1048576); // (768,384)
  bf16* FC2AT = (bf16*)(ws + (size_t)165 * 1048576); // (96,768)
  bf16* FC2BT = (bf16*)(ws + (size_t)166 * 1048576); // (192,96)
  bf16* DWT   = (bf16*)(ws + (size_t)167 * 1048576); // (27,768)
  int* FLAG   = (int*)(ws + (size_t)200 * 1048576);

  // 0. dtype detect + weight transposes
  detect_kernel<<<1, 64, 0, stream>>>((const unsigned short*)x, FLAG);
  transpose_kernel<<<432, 256, 0, stream>>>(qkv_w, QKVT, 192, 576, FLAG);
  transpose_kernel<<<144, 256, 0, stream>>>(proj_w, PROJT, 192, 192, FLAG);
  transpose_kernel<<<288, 256, 0, stream>>>(fc1_A, FC1AT, 192, 384, FLAG);
  transpose_kernel<<<1152, 256, 0, stream>>>(fc1_Bw, FC1BT, 384, 768, FLAG);
  transpose_kernel<<<288, 256, 0, stream>>>(fc2_A, FC2AT, 768, 96, FLAG);
  transpose_kernel<<<72, 256, 0, stream>>>(fc2_Bw, FC2BT, 96, 192, FLAG);
  dwT_kernel<<<81, 256, 0, stream>>>(dw_w, DWT, FLAG);
  // 1. LN1 + window gather -> SCR (H1)
  ln_kernel<<<N_TOK / 4, 256, 0, stream>>>(x, n1g, n1b, SCR, 1, 0, FLAG);
  // 2. QKV gemm, scatter to q/k/v planes
  mfma_gemm<<<dim3(9, 512), 256, 0, stream>>>(SCR, QKVT, qkv_b, nullptr, QKV,
                                              576, 192, 192, 0, 2, 0, FLAG);
  // 3. MFMA windowed attention -> SCR (ATT)
  attn_mfma_kernel<<<dim3(6, 256), 256, 0, stream>>>(QKV, relb, SCR, FLAG);
  // 4. proj + residual(x), window -> natural -> X1
  mfma_gemm<<<dim3(3, 512), 256, 0, stream>>>(SCR, PROJT, proj_b, x, X1,
                                              192, 192, 192, 0, 3, 0, FLAG);
  // 5. LN2 -> SCR (H2)
  ln_kernel<<<N_TOK / 4, 256, 0, stream>>>(X1, n2g, n2b, SCR, 0, 1, FLAG);
  // 6. fc1_A -> T1
  mfma_gemm<<<dim3(6, 512), 256, 0, stream>>>(SCR, FC1AT, nullptr, nullptr, T1,
                                              384, 192, 192, 0, 0, 0, FLAG);
  // 7. zero T2
  zero_kernel<<<6144, 256, 0, stream>>>((float4*)T2);
  // 8. MixFFN middle, 4 x 192-channel chunks
  for (int k = 0; k < 4; ++k) {
    mfma_gemm<<<dim3(3, 512), 256, 0, stream>>>(T1, FC1BT + (size_t)192 * k * 384,
                                                fc1_Bb, nullptr, F1c,
                                                192, 384, 384, 0, 0, (size_t)192 * k, FLAG);
    dwconv8_kernel<<<6144, 256, 0, stream>>>(F1c, DWT, dw_b, F2c, 192 * k, FLAG);
    mfma_gemm<<<dim3(2, 512), 256, 0, stream>>>(F2c, FC2AT, nullptr, nullptr, T2,
                                                96, 192, 768, 192 * k, 4, 0, FLAG);
  }
  // 9. T2 -> bf16
  cvt_kernel<<<24576, 256, 0, stream>>>(T2, T2bf);
  // 10. fc2_B + residual(X1) -> out
  mfma_gemm<<<dim3(3, 512), 256, 0, stream>>>(T2bf, FC2BT, fc2_Bb, X1, d_out,
                                              192, 96, 96, 0, 1, 0, FLAG);
}

// Round 8
// 875.648 us; speedup vs baseline: 18.4377x; 1.2263x over previous
//
#include <hip/hip_runtime.h>
#include <hip/hip_bf16.h>

typedef __hip_bfloat16 bf16;
typedef __attribute__((ext_vector_type(8))) short short8;
typedef __attribute__((ext_vector_type(4))) float f32x4;

#define N_TOK 65536
#define C_DIM 192
#define SCALE 0.17677669529663687f

__device__ __forceinline__ float b2f(bf16 v) { return __bfloat162float(v); }
__device__ __forceinline__ bf16 f2b(float v) { return __float2bfloat16(v); }
__device__ __forceinline__ float ldA(const void* p, size_t i, int f32) {
  return f32 ? ((const float*)p)[i] : b2f(((const bf16*)p)[i]);
}
__device__ __forceinline__ float s2f(short s) { union { short s; bf16 b; } u; u.s = s; return b2f(u.b); }

// ---------------- dtype detector (silent) ----------------
__global__ void detect_kernel(const unsigned short* __restrict__ xh, int* __restrict__ flag) {
  if (threadIdx.x == 0) {
    int crazy = 0;
    for (int i = 0; i < 256; ++i) {
      int e = (xh[i] >> 7) & 0xFF;
      if (e >= 0xF0 || (e >= 1 && e <= 0x60)) ++crazy;
    }
    *flag = (crazy >= 16) ? 1 : 0;
  }
}

// ---------------- weight transpose: in (K,N) adaptive -> out (N,K) bf16 ----------------
__global__ __launch_bounds__(256) void transpose_kernel(const void* __restrict__ in,
    bf16* __restrict__ out, int K, int N, const int* __restrict__ flag) {
  int f32 = *flag;
  int idx = blockIdx.x * 256 + threadIdx.x;
  if (idx >= K * N) return;
  int n = idx / K, k = idx - n * K;
  out[idx] = f2b(ldA(in, (size_t)k * N + n, f32));
}

// ---------------- dw weight transpose: (768,27) adaptive -> (27,768) bf16 ----------------
__global__ __launch_bounds__(256) void dwT_kernel(const void* __restrict__ in,
    bf16* __restrict__ out, const int* __restrict__ flag) {
  int f32 = *flag;
  int idx = blockIdx.x * 256 + threadIdx.x;
  if (idx >= 27 * 768) return;
  int tap = idx / 768, c = idx - tap * 768;
  out[idx] = f2b(ldA(in, (size_t)c * 27 + tap, f32));
}

// ---------------- LayerNorm ----------------
__global__ __launch_bounds__(256) void ln_kernel(const void* __restrict__ x,
    const void* __restrict__ g, const void* __restrict__ b, bf16* __restrict__ out,
    int windowize, int xIsBf16Fixed, const int* __restrict__ flag) {
  int wf32 = *flag;
  int f32 = xIsBf16Fixed ? 0 : wf32;
  int token = blockIdx.x * 4 + (threadIdx.x >> 6);
  int lane = threadIdx.x & 63;
  size_t base = (size_t)token * C_DIM;
  float v0 = ldA(x, base + lane, f32);
  float v1 = ldA(x, base + lane + 64, f32);
  float v2 = ldA(x, base + lane + 128, f32);
  float s = v0 + v1 + v2;
  float s2 = v0 * v0 + v1 * v1 + v2 * v2;
  #pragma unroll
  for (int o = 32; o > 0; o >>= 1) { s += __shfl_xor(s, o, 64); s2 += __shfl_xor(s2, o, 64); }
  float mu = s * (1.f / 192.f);
  float var = s2 * (1.f / 192.f) - mu * mu;
  float rstd = rsqrtf(var + 1e-5f);
  int row = token;
  if (windowize) {
    int d = token >> 12, h = (token >> 6) & 63, w = token & 63;
    int win = ((d >> 2) << 6) + ((h >> 3) << 3) + (w >> 3);
    int t = ((d & 3) << 6) + ((h & 7) << 3) + (w & 7);
    row = win * 256 + t;
  }
  bf16* po = out + (size_t)row * C_DIM;
  po[lane]       = f2b((v0 - mu) * rstd * ldA(g, lane, wf32)       + ldA(b, lane, wf32));
  po[lane + 64]  = f2b((v1 - mu) * rstd * ldA(g, lane + 64, wf32)  + ldA(b, lane + 64, wf32));
  po[lane + 128] = f2b((v2 - mu) * rstd * ldA(g, lane + 128, wf32) + ldA(b, lane + 128, wf32));
}

// ---------------- MFMA GEMM with XCD-aware block swizzle ----------------
// BM=128, BN=64, BK=32; grid (ncb, 512). Flat block id remapped so all ncb
// column-blocks of a row-tile share flat%8 -> same XCD -> A-tile in that L2.
// mode 0: out bf16 = v (+bias)
// mode 1: out adaptive = b2f(res bf16) + v + bias    (final output)
// mode 3: out bf16 natural = res(adaptive) + v + bias, window->natural remap (proj)
__global__ __launch_bounds__(256) void mfma_gemm(const bf16* __restrict__ A,
    const bf16* __restrict__ BT, const void* __restrict__ bias,
    const void* __restrict__ res, void* __restrict__ out,
    int Nc, int K, int ldk, int mode, const int* __restrict__ flag) {
  int f32 = *flag;
  __shared__ short As[128 * 40];
  __shared__ short Bs[64 * 40];
  int tid = threadIdx.x;
  int wave = tid >> 6, lane = tid & 63;
  int wm = wave >> 1, wn = wave & 1;
  int lr = lane & 15, quad = lane >> 4;
  // XCD swizzle: rowTile = group*8 + flat%8, col = (flat % (8*ncb)) / 8
  int ncb = gridDim.x;
  int flat = blockIdx.x + ncb * blockIdx.y;
  int group = flat / (8 * ncb);
  int r = flat - group * 8 * ncb;
  int rowBase = (group * 8 + (r & 7)) * 128;
  int colBase = (r >> 3) * 64;
  f32x4 acc[4][2];
  #pragma unroll
  for (int i = 0; i < 4; ++i)
    #pragma unroll
    for (int j = 0; j < 2; ++j) acc[i][j] = f32x4{0.f, 0.f, 0.f, 0.f};

  for (int k0 = 0; k0 < K; k0 += 32) {
    #pragma unroll
    for (int it = 0; it < 2; ++it) {
      int idx = tid + it * 256;
      int row = idx >> 2, kc = (idx & 3) * 8;
      uint4 v = *(const uint4*)(A + (size_t)(rowBase + row) * K + k0 + kc);
      *(uint4*)&As[row * 40 + kc] = v;
    }
    {
      int n = tid >> 2, kc = (tid & 3) * 8;
      uint4 v = uint4{0u, 0u, 0u, 0u};
      if (colBase + n < Nc)
        v = *(const uint4*)(BT + (size_t)(colBase + n) * ldk + k0 + kc);
      *(uint4*)&Bs[n * 40 + kc] = v;
    }
    __syncthreads();
    short8 af[4], bf[2];
    #pragma unroll
    for (int i = 0; i < 4; ++i)
      af[i] = *(const short8*)&As[(wm * 64 + i * 16 + lr) * 40 + quad * 8];
    #pragma unroll
    for (int j = 0; j < 2; ++j)
      bf[j] = *(const short8*)&Bs[(wn * 32 + j * 16 + lr) * 40 + quad * 8];
    #pragma unroll
    for (int i = 0; i < 4; ++i)
      #pragma unroll
      for (int j = 0; j < 2; ++j)
        acc[i][j] = __builtin_amdgcn_mfma_f32_16x16x32_bf16(af[i], bf[j], acc[i][j], 0, 0, 0);
    __syncthreads();
  }

  #pragma unroll
  for (int i = 0; i < 4; ++i) {
    #pragma unroll
    for (int j = 0; j < 2; ++j) {
      #pragma unroll
      for (int r4 = 0; r4 < 4; ++r4) {
        int row = rowBase + wm * 64 + i * 16 + quad * 4 + r4;
        int c = colBase + wn * 32 + j * 16 + lr;
        if (c >= Nc) continue;
        float v = acc[i][j][r4];
        if (bias) v += ldA(bias, c, f32);
        if (mode == 0) {
          ((bf16*)out)[(size_t)row * Nc + c] = f2b(v);
        } else if (mode == 1) {
          float o = b2f(((const bf16*)res)[(size_t)row * Nc + c]) + v;
          if (f32) ((float*)out)[(size_t)row * Nc + c] = o;
          else     ((bf16*)out)[(size_t)row * Nc + c] = f2b(o);
        } else {  // mode 3: proj + residual, window -> natural
          int win = row >> 8, t = row & 255;
          int d = ((win >> 6) << 2) + (t >> 6);
          int h = (((win >> 3) & 7) << 3) + ((t >> 3) & 7);
          int w = ((win & 7) << 3) + (t & 7);
          int n = (d << 12) + (h << 6) + w;
          ((bf16*)out)[(size_t)n * C_DIM + c] = f2b(ldA(res, (size_t)n * C_DIM + c, f32) + v);
        }
      }
    }
  }
}

// ---------------- MFMA attention from row-major QKV (win-token, 576) ----------------
__global__ __launch_bounds__(256) void attn_mfma_kernel(const bf16* __restrict__ qkvr,
    const void* __restrict__ rel_bias, bf16* __restrict__ out,
    const int* __restrict__ flag) {
  int f32 = *flag;
  __shared__ bf16 sK[256 * 40];
  __shared__ bf16 sVT[32 * 264];
  __shared__ bf16 sP[4][64 * 40];
  __shared__ float sb[1575];
  __shared__ int  sgb[256];
  int head = blockIdx.x, win = blockIdx.y;
  const bf16* base = qkvr + (size_t)win * 256 * 576;
  int qoff = head * 32, koff = 192 + head * 32, voff = 384 + head * 32;
  int tid = threadIdx.x;
  int wave = tid >> 6, lane = tid & 63;
  int lr = lane & 15, quad = lane >> 4;

  #pragma unroll
  for (int it = 0; it < 4; ++it) {
    int idx = tid + it * 256;              // 0..1023
    int tok = idx >> 2, kc = (idx & 3) * 8;
    uint4 v = *(const uint4*)(base + (size_t)tok * 576 + koff + kc);
    *(uint4*)&sK[tok * 40 + kc] = v;
  }
  for (int idx = tid; idx < 8192; idx += 256) {
    int tok = idx >> 5, hd = idx & 31;
    sVT[hd * 264 + tok] = base[(size_t)tok * 576 + voff + hd];
  }
  for (int idx = tid; idx < 1575; idx += 256) sb[idx] = ldA(rel_bias, (size_t)idx * 6 + head, f32);
  {
    int t = tid & 255;
    int d = ((win >> 6) << 2) + (t >> 6);
    int h = (((win >> 3) & 7) << 3) + ((t >> 3) & 7);
    int w = ((win & 7) << 3) + (t & 7);
    int d2 = (d + 2) & 15, h2 = (h + 4) & 63, w2 = (w + 4) & 63;
    int g = ((d2 >> 2) << 6) + ((h2 >> 3) << 3) + (w2 >> 3);
    int td = t >> 6, th = (t >> 3) & 7, tw = t & 7;
    int bse = (td * 15 + th) * 15 + tw;
    sgb[t] = (g << 12) | bse;
  }
  __syncthreads();

  int wm = wave * 64;
  short8 aq[4];
  #pragma unroll
  for (int i = 0; i < 4; ++i)
    aq[i] = *(const short8*)(base + (size_t)(wm + i * 16 + lr) * 576 + qoff + quad * 8);
  int rinfo[16];
  #pragma unroll
  for (int i = 0; i < 4; ++i)
    #pragma unroll
    for (int r = 0; r < 4; ++r)
      rinfo[i * 4 + r] = sgb[wm + i * 16 + quad * 4 + r];

  f32x4 acc_o[4][2], acc_l[4];
  #pragma unroll
  for (int i = 0; i < 4; ++i) {
    acc_l[i] = f32x4{0.f, 0.f, 0.f, 0.f};
    #pragma unroll
    for (int j = 0; j < 2; ++j) acc_o[i][j] = f32x4{0.f, 0.f, 0.f, 0.f};
  }
  short8 bones;
  #pragma unroll
  for (int j = 0; j < 8; ++j) bones[j] = (lr == 0) ? (short)0x3F80 : (short)0;

  for (int c = 0; c < 8; ++c) {
    short8 bk[2];
    #pragma unroll
    for (int jt = 0; jt < 2; ++jt)
      bk[jt] = *(const short8*)&sK[(c * 32 + jt * 16 + lr) * 40 + quad * 8];
    f32x4 s[4][2];
    #pragma unroll
    for (int i = 0; i < 4; ++i)
      #pragma unroll
      for (int jt = 0; jt < 2; ++jt) {
        s[i][jt] = f32x4{0.f, 0.f, 0.f, 0.f};
        s[i][jt] = __builtin_amdgcn_mfma_f32_16x16x32_bf16(aq[i], bk[jt], s[i][jt], 0, 0, 0);
      }
    int cinfo[2];
    #pragma unroll
    for (int jt = 0; jt < 2; ++jt) cinfo[jt] = sgb[c * 32 + jt * 16 + lr];
    #pragma unroll
    for (int i = 0; i < 4; ++i)
      #pragma unroll
      for (int jt = 0; jt < 2; ++jt)
        #pragma unroll
        for (int r = 0; r < 4; ++r) {
          int ri = rinfo[i * 4 + r], ci = cinfo[jt];
          float sc = s[i][jt][r] * SCALE + sb[(ri & 0xFFF) - (ci & 0xFFF) + 787];
          float p = ((ri >> 12) == (ci >> 12)) ? __expf(sc) : 0.f;
          sP[wave][(i * 16 + quad * 4 + r) * 40 + jt * 16 + lr] = f2b(p);
        }
    short8 ap[4];
    #pragma unroll
    for (int i = 0; i < 4; ++i)
      ap[i] = *(const short8*)&sP[wave][(i * 16 + lr) * 40 + quad * 8];
    short8 bv[2];
    #pragma unroll
    for (int jh = 0; jh < 2; ++jh)
      bv[jh] = *(const short8*)&sVT[(jh * 16 + lr) * 264 + c * 32 + quad * 8];
    #pragma unroll
    for (int i = 0; i < 4; ++i) {
      #pragma unroll
      for (int jh = 0; jh < 2; ++jh)
        acc_o[i][jh] = __builtin_amdgcn_mfma_f32_16x16x32_bf16(ap[i], bv[jh], acc_o[i][jh], 0, 0, 0);
      acc_l[i] = __builtin_amdgcn_mfma_f32_16x16x32_bf16(ap[i], bones, acc_l[i], 0, 0, 0);
    }
  }
  #pragma unroll
  for (int i = 0; i < 4; ++i) {
    #pragma unroll
    for (int r = 0; r < 4; ++r) {
      float l = __shfl(acc_l[i][r], lane & 48, 64);
      float inv = 1.f / l;
      int t = wm + i * 16 + quad * 4 + r;
      bf16* po = out + (size_t)(win * 256 + t) * C_DIM + head * 32;
      po[lr]      = f2b(acc_o[i][0][r] * inv);
      po[16 + lr] = f2b(acc_o[i][1][r] * inv);
    }
  }
}

// ---------------- Depthwise conv + GELU, full 768 channels, 8 per thread --------------
__global__ __launch_bounds__(256) void dwconv8_kernel(const bf16* __restrict__ in,
    const bf16* __restrict__ wT, const void* __restrict__ wb, bf16* __restrict__ out,
    const int* __restrict__ flag) {
  int f32 = *flag;
  int idx = blockIdx.x * 256 + threadIdx.x;   // 65536 * 96
  int n = idx / 96, g = idx - n * 96;
  int c0 = g * 8;
  int d = n >> 12, h = (n >> 6) & 63, w = n & 63;
  float acc[8];
  #pragma unroll
  for (int e = 0; e < 8; ++e) acc[e] = ldA(wb, c0 + e, f32);
  #pragma unroll
  for (int kd = 0; kd < 3; ++kd) {
    int dd = d + kd - 1;
    if ((unsigned)dd >= 16u) continue;
    #pragma unroll
    for (int kh = 0; kh < 3; ++kh) {
      int hh = h + kh - 1;
      if ((unsigned)hh >= 64u) continue;
      #pragma unroll
      for (int kw = 0; kw < 3; ++kw) {
        int ww = w + kw - 1;
        if ((unsigned)ww >= 64u) continue;
        int nbr = (dd << 12) + (hh << 6) + ww;
        int tap = kd * 9 + kh * 3 + kw;
        short8 xv = *(const short8*)(in + (size_t)nbr * 768 + c0);
        short8 wv = *(const short8*)(wT + tap * 768 + c0);
        #pragma unroll
        for (int e = 0; e < 8; ++e) acc[e] += s2f(xv[e]) * s2f(wv[e]);
      }
    }
  }
  bf16* po = out + (size_t)n * 768 + c0;
  #pragma unroll
  for (int e = 0; e < 8; ++e) {
    float s = acc[e];
    po[e] = f2b(0.5f * s * (1.f + erff(s * 0.70710678118654752f)));
  }
}

extern "C" void kernel_launch(void* const* d_in, const int* in_sizes, int n_in,
                              void* d_out, int out_size, void* d_ws, size_t ws_size,
                              hipStream_t stream) {
  const void* x      = d_in[0];
  const void* n1g    = d_in[1];
  const void* n1b    = d_in[2];
  const void* qkv_w  = d_in[3];
  const void* qkv_b  = d_in[4];
  const void* relb   = d_in[5];
  const void* proj_w = d_in[6];
  const void* proj_b = d_in[7];
  const void* n2g    = d_in[8];
  const void* n2b    = d_in[9];
  const void* fc1_A  = d_in[10];
  const void* fc1_Bw = d_in[11];
  const void* fc1_Bb = d_in[12];
  const void* dw_w   = d_in[13];
  const void* dw_b   = d_in[14];
  const void* fc2_A  = d_in[15];
  const void* fc2_Bw = d_in[16];
  const void* fc2_Bb = d_in[17];

  // ws layout (MiB), 256 total. Lifetimes:
  //  QKVR [24,96)  : steps 2-3, then dead
  //  X1   [0,24)   : step 4 .. end
  //  T1   [24,72)  : step 6 -> fc1_B, then dead
  //  F1   [120,216): fc1_B -> dwconv, then dead
  //  F2   [24,120) : dwconv -> fc2_A (overwrites dead T1/QKVR)
  //  T2bf [216,228): fc2_A -> fc2_B
  //  weights [228..236), FLAG at 255
  char* ws = (char*)d_ws;
  bf16* SCR  = (bf16*)d_out;                         // H1 / ATT / H2 scratch
  bf16* X1   = (bf16*)(ws);
  bf16* QKVR = (bf16*)(ws + (size_t)24 * 1048576);
  bf16* T1   = (bf16*)(ws + (size_t)24 * 1048576);
  bf16* F2   = (bf16*)(ws + (size_t)24 * 1048576);
  bf16* F1   = (bf16*)(ws + (size_t)120 * 1048576);
  bf16* T2bf = (bf16*)(ws + (size_t)216 * 1048576);
  bf16* QKVT  = (bf16*)(ws + (size_t)228 * 1048576); // (576,192)
  bf16* PROJT = (bf16*)(ws + (size_t)229 * 1048576); // (192,192)
  bf16* FC1AT = (bf16*)(ws + (size_t)230 * 1048576); // (384,192)
  bf16* FC1BT = (bf16*)(ws + (size_t)231 * 1048576); // (768,384) 0.56 MiB
  bf16* FC2AT = (bf16*)(ws + (size_t)233 * 1048576); // (96,768)
  bf16* FC2BT = (bf16*)(ws + (size_t)234 * 1048576); // (192,96)
  bf16* DWT   = (bf16*)(ws + (size_t)235 * 1048576); // (27,768)
  int* FLAG   = (int*)(ws + (size_t)255 * 1048576);

  // 0. dtype detect + weight transposes
  detect_kernel<<<1, 64, 0, stream>>>((const unsigned short*)x, FLAG);
  transpose_kernel<<<432, 256, 0, stream>>>(qkv_w, QKVT, 192, 576, FLAG);
  transpose_kernel<<<144, 256, 0, stream>>>(proj_w, PROJT, 192, 192, FLAG);
  transpose_kernel<<<288, 256, 0, stream>>>(fc1_A, FC1AT, 192, 384, FLAG);
  transpose_kernel<<<1152, 256, 0, stream>>>(fc1_Bw, FC1BT, 384, 768, FLAG);
  transpose_kernel<<<288, 256, 0, stream>>>(fc2_A, FC2AT, 768, 96, FLAG);
  transpose_kernel<<<72, 256, 0, stream>>>(fc2_Bw, FC2BT, 96, 192, FLAG);
  dwT_kernel<<<81, 256, 0, stream>>>(dw_w, DWT, FLAG);
  // 1. LN1 + window gather -> SCR (H1)
  ln_kernel<<<N_TOK / 4, 256, 0, stream>>>(x, n1g, n1b, SCR, 1, 0, FLAG);
  // 2. QKV gemm -> row-major QKVR (win-token, 576)
  mfma_gemm<<<dim3(9, 512), 256, 0, stream>>>(SCR, QKVT, qkv_b, nullptr, QKVR,
                                              576, 192, 192, 0, FLAG);
  // 3. MFMA windowed attention -> SCR (ATT)
  attn_mfma_kernel<<<dim3(6, 256), 256, 0, stream>>>(QKVR, relb, SCR, FLAG);
  // 4. proj + residual(x), window -> natural -> X1
  mfma_gemm<<<dim3(3, 512), 256, 0, stream>>>(SCR, PROJT, proj_b, x, X1,
                                              192, 192, 192, 3, FLAG);
  // 5. LN2 -> SCR (H2)
  ln_kernel<<<N_TOK / 4, 256, 0, stream>>>(X1, n2g, n2b, SCR, 0, 1, FLAG);
  // 6. fc1_A: (N,192)@(192,384) -> T1
  mfma_gemm<<<dim3(6, 512), 256, 0, stream>>>(SCR, FC1AT, nullptr, nullptr, T1,
                                              384, 192, 192, 0, FLAG);
  // 7. fc1_B: (N,384)@(384,768)+b -> F1
  mfma_gemm<<<dim3(12, 512), 256, 0, stream>>>(T1, FC1BT, fc1_Bb, nullptr, F1,
                                               768, 384, 384, 0, FLAG);
  // 8. depthwise conv + GELU -> F2
  dwconv8_kernel<<<24576, 256, 0, stream>>>(F1, DWT, dw_b, F2, FLAG);
  // 9. fc2_A: (N,768)@(768,96) -> T2bf
  mfma_gemm<<<dim3(2, 512), 256, 0, stream>>>(F2, FC2AT, nullptr, nullptr, T2bf,
                                              96, 768, 768, 0, FLAG);
  // 10. fc2_B + residual(X1) -> out
  mfma_gemm<<<dim3(3, 512), 256, 0, stream>>>(T2bf, FC2BT, fc2_Bb, X1, d_out,
                                              192, 96, 96, 1, FLAG);
}